// Round 1
// baseline (6267.408 us; speedup 1.0000x reference)
//
#include <hip/hip_runtime.h>
#include <math.h>

#define B_    256
#define N_    100
#define OBJD  2048
#define L_    14
#define EMBD  300
#define H_    1024
#define H3    3072
#define NANS_ 3129

// ---------------------------------------------------------------- generic GEMM
// C[M,N] = epi(act(A[M,K] @ Bm[K,N] + bias))   row-major, batched over blockIdx.z
// ACT: 0 none, 1 relu, 2 tanh.  EPI: 0 none, 1 add src, 2 mul src.
// GATHER: A row m is A + gidx[m]*lda (embedding gather).
template<int BM,int BN,int BK,int TM,int TN,int ACT,int EPI,bool GATHER>
__global__ __launch_bounds__(256)
void gemm_f32(const float* __restrict__ A, long long sA, int lda,
              const float* __restrict__ Bm, long long sB, int ldb,
              const float* __restrict__ bias,
              const float* __restrict__ src, long long sSrc, int ldsrc,
              float* __restrict__ C, long long sC, int ldc,
              int M, int N, int K, const int* __restrict__ gidx)
{
    static_assert((BM*BK)%1024==0 && (BK*BN)%1024==0 && (BM/TM)*(BN/TN)==256, "cfg");
    constexpr int AV = (BM*BK)/1024, BV = (BK*BN)/1024;
    __shared__ float As[BK][BM+4];
    __shared__ float Bs[BK][BN+4];
    const int bz = blockIdx.z;
    A  += (long long)bz * sA;
    Bm += (long long)bz * sB;
    C  += (long long)bz * sC;
    if (EPI) src += (long long)bz * sSrc;

    const int tid = threadIdx.x;
    const int m0 = blockIdx.y * BM, n0 = blockIdx.x * BN;
    const int tx = tid % (BN/TN), ty = tid / (BN/TN);
    const bool bvec = ((ldb & 3) == 0);

    float acc[TM][TN];
#pragma unroll
    for (int i=0;i<TM;i++)
#pragma unroll
      for (int j=0;j<TN;j++) acc[i][j] = 0.f;

    for (int k0 = 0; k0 < K; k0 += BK) {
        // ---- load A tile (BM x BK)
#pragma unroll
        for (int u=0; u<AV; u++) {
            const int flat = (tid + u*256) * 4;
            const int r = flat / BK, c = flat % BK;
            const int gr = m0 + r, gk = k0 + c;
            float4 a4 = make_float4(0.f,0.f,0.f,0.f);
            if (gr < M) {
                const float* arow = GATHER ? (A + (long long)gidx[gr]*lda)
                                           : (A + (long long)gr*lda);
                if (gk + 3 < K) a4 = *(const float4*)(arow + gk);
                else {
                    float t0[4] = {0.f,0.f,0.f,0.f};
#pragma unroll
                    for (int i=0;i<4;i++) if (gk+i < K) t0[i] = arow[gk+i];
                    a4 = make_float4(t0[0],t0[1],t0[2],t0[3]);
                }
            }
            As[c+0][r]=a4.x; As[c+1][r]=a4.y; As[c+2][r]=a4.z; As[c+3][r]=a4.w;
        }
        // ---- load B tile (BK x BN)
#pragma unroll
        for (int u=0; u<BV; u++) {
            const int flat = (tid + u*256) * 4;
            const int r = flat / BN, c = flat % BN;
            const int gk = k0 + r, gc = n0 + c;
            float4 b4 = make_float4(0.f,0.f,0.f,0.f);
            if (gk < K) {
                const float* brow = Bm + (long long)gk * ldb;
                if (bvec && (gc + 3 < N)) b4 = *(const float4*)(brow + gc);
                else {
                    float t0[4] = {0.f,0.f,0.f,0.f};
#pragma unroll
                    for (int i=0;i<4;i++) if (gc+i < N) t0[i] = brow[gc+i];
                    b4 = make_float4(t0[0],t0[1],t0[2],t0[3]);
                }
            }
            Bs[r][c+0]=b4.x; Bs[r][c+1]=b4.y; Bs[r][c+2]=b4.z; Bs[r][c+3]=b4.w;
        }
        __syncthreads();
        // ---- compute
#pragma unroll
        for (int kk=0;kk<BK;kk++) {
            float a[TM], b[TN];
#pragma unroll
            for (int p=0;p<TM/4;p++) {
                float4 t4 = *(const float4*)&As[kk][ty*TM + 4*p];
                a[4*p]=t4.x; a[4*p+1]=t4.y; a[4*p+2]=t4.z; a[4*p+3]=t4.w;
            }
#pragma unroll
            for (int p=0;p<TN/4;p++) {
                float4 t4 = *(const float4*)&Bs[kk][tx*TN + 4*p];
                b[4*p]=t4.x; b[4*p+1]=t4.y; b[4*p+2]=t4.z; b[4*p+3]=t4.w;
            }
#pragma unroll
            for (int i=0;i<TM;i++)
#pragma unroll
                for (int j=0;j<TN;j++) acc[i][j] = fmaf(a[i], b[j], acc[i][j]);
        }
        __syncthreads();
    }
    // ---- epilogue
#pragma unroll
    for (int i=0;i<TM;i++) {
        const int r = m0 + ty*TM + i;
        if (r >= M) continue;
#pragma unroll
        for (int j=0;j<TN;j++) {
            const int c = n0 + tx*TN + j;
            if (c >= N) continue;
            float val = acc[i][j];
            if (bias) val += bias[c];
            if (ACT == 1) val = fmaxf(val, 0.f);
            else if (ACT == 2) val = tanhf(val);
            if (EPI == 1) val += src[(long long)r*ldsrc + c];
            else if (EPI == 2) val *= src[(long long)r*ldsrc + c];
            C[(long long)r*ldc + c] = val;
        }
    }
}

// ---------------------------------------------------------------- GRU gate math
__global__ __launch_bounds__(256)
void gru_gate_kernel(const float* __restrict__ gi, int t,
                     const float* __restrict__ gh,      // null for t==0 (h==0)
                     const float* __restrict__ bhh,
                     const float* __restrict__ hIn, float* __restrict__ hOut)
{
    const int idx = blockIdx.x*256 + threadIdx.x;       // < B_*H_
    const int b = idx >> 10, j = idx & (H_-1);
    const float* gib = gi + ((long long)b*L_ + t)*H3;
    const float ir = gib[j], iz = gib[j+H_], inn = gib[j+2*H_];
    float hr, hz, hn;
    if (gh) { const float* ghb = gh + (long long)b*H3; hr=ghb[j]; hz=ghb[j+H_]; hn=ghb[j+2*H_]; }
    else    { hr=bhh[j]; hz=bhh[j+H_]; hn=bhh[j+2*H_]; }
    const float r = 1.f/(1.f+expf(-(ir+hr)));
    const float z = 1.f/(1.f+expf(-(iz+hz)));
    const float n = tanhf(inn + r*hn);
    hOut[idx] = (1.f - z)*n + z*hIn[idx];
}

// ---------------------------------------------------------------- s_proj = tanh(b4 @ ws_b)
__global__ __launch_bounds__(256)
void sproj_kernel(const float* __restrict__ bIn, const float* __restrict__ wsB,
                  float* __restrict__ sProj)
{
    const int row = blockIdx.x;                          // b*N_+n
    const float* br = bIn + (long long)row * 6;
    const float b0=br[0], b1=br[1], b2=br[2], b3=br[3];
    for (int h = threadIdx.x; h < H_; h += 256) {
        float val = b0*wsB[h] + b1*wsB[H_+h] + b2*wsB[2*H_+h] + b3*wsB[3*H_+h];
        sProj[(long long)row*H_ + h] = tanhf(val);
    }
}

// ---------------------------------------------------------------- fused Gram: s_rel + v_rel
__global__ __launch_bounds__(256)
void gram_rel_kernel(const float* __restrict__ sProj, const float* __restrict__ sQ,
                     const float* __restrict__ vProj, const float* __restrict__ vQ,
                     float* __restrict__ rel)
{
    __shared__ float As[16][68];
    __shared__ float Bs[16][68];
    const int b = blockIdx.z;
    const int n0 = blockIdx.y * 64, m0 = blockIdx.x * 64;
    const int tid = threadIdx.x;
    const int lr = tid / 4, lk = (tid % 4) * 4;
    const int tx = tid % 16, ty = tid / 16;
    float acc[4][4];
#pragma unroll
    for (int i=0;i<4;i++)
#pragma unroll
      for (int j=0;j<4;j++) acc[i][j]=0.f;

    for (int pass=0; pass<2; ++pass) {
        const float* P  = pass ? vProj : sProj;
        const float* Q  = (pass ? vQ : sQ) + (long long)b * H_;
        const float* Pb = P + (long long)b * N_ * H_;
        for (int k0=0; k0<H_; k0+=16) {
            const float4 qv = *(const float4*)(Q + k0 + lk);
            float4 a4 = make_float4(0,0,0,0), b4 = make_float4(0,0,0,0);
            if (n0 + lr < N_) a4 = *(const float4*)(Pb + (long long)(n0+lr)*H_ + k0 + lk);
            if (m0 + lr < N_) b4 = *(const float4*)(Pb + (long long)(m0+lr)*H_ + k0 + lk);
            As[lk+0][lr]=a4.x*qv.x; As[lk+1][lr]=a4.y*qv.y; As[lk+2][lr]=a4.z*qv.z; As[lk+3][lr]=a4.w*qv.w;
            Bs[lk+0][lr]=b4.x; Bs[lk+1][lr]=b4.y; Bs[lk+2][lr]=b4.z; Bs[lk+3][lr]=b4.w;
            __syncthreads();
#pragma unroll
            for (int kk=0;kk<16;kk++){
                const float4 av4 = *(const float4*)&As[kk][ty*4];
                const float4 bv4 = *(const float4*)&Bs[kk][tx*4];
                const float a[4]={av4.x,av4.y,av4.z,av4.w};
                const float bb[4]={bv4.x,bv4.y,bv4.z,bv4.w};
#pragma unroll
                for (int i=0;i<4;i++)
#pragma unroll
                  for (int j=0;j<4;j++) acc[i][j] = fmaf(a[i],bb[j],acc[i][j]);
            }
            __syncthreads();
        }
    }
#pragma unroll
    for (int i=0;i<4;i++){
        const int n = n0 + ty*4 + i; if (n>=N_) continue;
#pragma unroll
        for (int j=0;j<4;j++){
            const int m = m0 + tx*4 + j; if (m>=N_) continue;
            rel[((long long)b*N_ + n)*N_ + m] = acc[i][j];
        }
    }
}

// ---------------------------------------------------------------- softmax over m (rows of 100)
__global__ __launch_bounds__(256)
void softmax_m_kernel(float* __restrict__ rel)
{
    const int w = threadIdx.x >> 6, l = threadIdx.x & 63;
    float* r = rel + ((long long)blockIdx.x*4 + w)*N_;
    const float v0 = r[l];
    const float v1 = (l + 64 < N_) ? r[l+64] : -INFINITY;
    float mx = fmaxf(v0, v1);
    for (int s=32;s;s>>=1) mx = fmaxf(mx, __shfl_xor(mx, s));
    const float e0 = expf(v0-mx);
    const float e1 = (l+64<N_) ? expf(v1-mx) : 0.f;
    float sum = e0+e1;
    for (int s=32;s;s>>=1) sum += __shfl_xor(sum, s);
    const float inv = 1.f/sum;
    r[l] = e0*inv;
    if (l+64 < N_) r[l+64] = e1*inv;
}

// ---------------------------------------------------------------- att logits: (av*aq) @ wa_out
__global__ __launch_bounds__(256)
void att_logits_kernel(const float* __restrict__ av, const float* __restrict__ aq,
                       const float* __restrict__ waOut, float* __restrict__ out)
{
    const int w = threadIdx.x >> 6, l = threadIdx.x & 63;
    const int row = blockIdx.x*4 + w;                    // < B_*N_
    const int b = row / N_;
    const float* avr = av + (long long)row*H_;
    const float* aqr = aq + (long long)b*H_;
    float acc = 0.f;
#pragma unroll
    for (int i=0;i<4;i++){
        const int h = i*256 + l*4;
        const float4 a4 = *(const float4*)(avr+h);
        const float4 q4 = *(const float4*)(aqr+h);
        const float4 w4 = *(const float4*)(waOut+h);
        acc += a4.x*q4.x*w4.x + a4.y*q4.y*w4.y + a4.z*q4.z*w4.z + a4.w*q4.w*w4.w;
    }
    for (int s=32;s;s>>=1) acc += __shfl_xor(acc, s);
    if (l==0) out[row] = acc;
}

// ---------------------------------------------------------------- softmax over n (per b)
__global__ __launch_bounds__(128)
void softmax_n_kernel(const float* __restrict__ lg, float* __restrict__ att)
{
    __shared__ float s[128];
    const int b = blockIdx.x, t = threadIdx.x;
    const float v = (t < N_) ? lg[(long long)b*N_+t] : -INFINITY;
    s[t]=v; __syncthreads();
    for (int st=64;st;st>>=1){ if (t<st) s[t]=fmaxf(s[t],s[t+st]); __syncthreads(); }
    const float mx = s[0]; __syncthreads();
    const float e = (t<N_)? expf(v-mx) : 0.f;
    s[t]=e; __syncthreads();
    for (int st=64;st;st>>=1){ if (t<st) s[t]+=s[t+st]; __syncthreads(); }
    const float inv = 1.f/s[0];
    if (t<N_) att[(long long)b*N_+t] = e*inv;
}

// ---------------------------------------------------------------- v_emb = sum_n v_att*v2
__global__ __launch_bounds__(256)
void vemb_kernel(const float* __restrict__ att, const float* __restrict__ v2,
                 float* __restrict__ vEmb)
{
    __shared__ float sa[N_];
    const int b = blockIdx.y, dt = blockIdx.x, tid = threadIdx.x;
    if (tid < N_) sa[tid] = att[(long long)b*N_+tid];
    __syncthreads();
    const int d = dt*256 + tid;
    const float* vb = v2 + (long long)b*N_*OBJD + d;
    float acc = 0.f;
#pragma unroll 4
    for (int n=0;n<N_;n++) acc += sa[n]*vb[(long long)n*OBJD];
    vEmb[(long long)b*OBJD + d] = acc;
}

// ================================================================ launcher
extern "C" void kernel_launch(void* const* d_in, const int* in_sizes, int n_in,
                              void* d_out, int out_size, void* d_ws, size_t ws_size,
                              hipStream_t stream)
{
    const float* v      = (const float*)d_in[0];
    const float* bbox   = (const float*)d_in[1];
    const int*   q      = (const int*)  d_in[3];
    const float* emb    = (const float*)d_in[5];
    const float* wih    = (const float*)d_in[6];
    const float* whh    = (const float*)d_in[7];
    const float* bih    = (const float*)d_in[8];
    const float* bhh    = (const float*)d_in[9];
    const float* wq_net = (const float*)d_in[10];
    const float* bq_net = (const float*)d_in[11];
    const float* ws_b   = (const float*)d_in[12];
    const float* ws_q   = (const float*)d_in[13];
    const float* wv_v   = (const float*)d_in[14];
    const float* wv_q   = (const float*)d_in[15];
    const float* wa_v   = (const float*)d_in[16];
    const float* wa_q   = (const float*)d_in[17];
    const float* wa_out = (const float*)d_in[18];
    const float* wv_net = (const float*)d_in[19];
    const float* bv_net = (const float*)d_in[20];
    const float* wc1    = (const float*)d_in[21];
    const float* bc1    = (const float*)d_in[22];
    const float* wc2    = (const float*)d_in[23];
    const float* bc2    = (const float*)d_in[24];
    float* out = (float*)d_out;
    (void)in_sizes; (void)n_in; (void)out_size; (void)ws_size;

    float* ws = (float*)d_ws;
    size_t off = 0;
    auto alloc = [&](size_t n){ float* p = ws + off; off += (n + 63) & ~(size_t)63; return p; };
    float* gi    = alloc((size_t)B_*L_*H3);        // 44 MB
    float* h_a   = alloc((size_t)B_*H_);
    float* h_b   = alloc((size_t)B_*H_);
    float* gh    = alloc((size_t)B_*H3);
    float* qrepr = alloc((size_t)B_*H_);
    float* sq    = alloc((size_t)B_*H_);
    float* vqb   = alloc((size_t)B_*H_);
    float* aqb   = alloc((size_t)B_*H_);
    float* sproj = alloc((size_t)B_*N_*H_);        // 105 MB
    float* vproj = alloc((size_t)B_*N_*H_);        // 105 MB
    float* relb  = alloc((size_t)B_*N_*N_);        // 10 MB
    float* v2    = alloc((size_t)B_*N_*OBJD);      // 210 MB
    float* avb   = sproj;                          // reuse: s_proj dead after rel
    float* attl  = alloc((size_t)B_*N_);
    float* vatt  = alloc((size_t)B_*N_);
    float* vemb  = alloc((size_t)B_*OBJD);
    float* joint = alloc((size_t)B_*H_);
    float* c1h   = alloc((size_t)B_*2*H_);

    hipMemsetAsync(h_a, 0, (size_t)B_*H_*sizeof(float), stream);

    // gi = emb[q] @ wih + bih     [3584 x 3072], K=300
    {
        dim3 g(H3/128, (B_*L_+127)/128, 1);
        gemm_f32<128,128,16,8,8,0,0,true><<<g,256,0,stream>>>(
            emb,0,EMBD, wih,0,H3, bih, nullptr,0,0, gi,0,H3, B_*L_, H3, EMBD, q);
    }
    // GRU: 14 steps, ping-pong h
    float* hin = h_a; float* hout = h_b;
    for (int t=0;t<L_;t++){
        const float* ghp = nullptr;
        if (t>0){
            dim3 g(H3/64, B_/64, 1);
            gemm_f32<64,64,16,4,4,0,0,false><<<g,256,0,stream>>>(
                hin,0,H_, whh,0,H3, bhh, nullptr,0,0, gh,0,H3, B_, H3, H_, nullptr);
            ghp = gh;
        }
        gru_gate_kernel<<<(B_*H_)/256,256,0,stream>>>(gi, t, ghp, bhh, hin, hout);
        float* tmp=hin; hin=hout; hout=tmp;
    }
    const float* qemb = hin;

    // four q-side projections
    {
        dim3 g(H_/64, B_/64, 1);
        gemm_f32<64,64,16,4,4,1,0,false><<<g,256,0,stream>>>(qemb,0,H_, wq_net,0,H_, bq_net, nullptr,0,0, qrepr,0,H_, B_,H_,H_, nullptr);
        gemm_f32<64,64,16,4,4,2,0,false><<<g,256,0,stream>>>(qemb,0,H_, ws_q,0,H_, nullptr, nullptr,0,0, sq,0,H_, B_,H_,H_, nullptr);
        gemm_f32<64,64,16,4,4,2,0,false><<<g,256,0,stream>>>(qemb,0,H_, wv_q,0,H_, nullptr, nullptr,0,0, vqb,0,H_, B_,H_,H_, nullptr);
        gemm_f32<64,64,16,4,4,1,0,false><<<g,256,0,stream>>>(qemb,0,H_, wa_q,0,H_, nullptr, nullptr,0,0, aqb,0,H_, B_,H_,H_, nullptr);
    }
    sproj_kernel<<<B_*N_,256,0,stream>>>(bbox, ws_b, sproj);
    // v_proj = tanh(v @ wv_v)
    {
        dim3 g(H_/128, (B_*N_)/128, 1);
        gemm_f32<128,128,16,8,8,2,0,false><<<g,256,0,stream>>>(
            v,0,OBJD, wv_v,0,H_, nullptr, nullptr,0,0, vproj,0,H_, B_*N_, H_, OBJD, nullptr);
    }
    // rel logits = s_gram + v_gram
    {
        dim3 g(2,2,B_);
        gram_rel_kernel<<<g,256,0,stream>>>(sproj, sq, vproj, vqb, relb);
    }
    softmax_m_kernel<<<(B_*N_)/4,256,0,stream>>>(relb);
    // v2 = rel @ v + v   (batched)
    {
        dim3 g(OBJD/64, (N_+63)/64, B_);
        gemm_f32<64,64,16,4,4,0,1,false><<<g,256,0,stream>>>(
            relb,(long long)N_*N_,N_, v,(long long)N_*OBJD,OBJD, nullptr,
            v,(long long)N_*OBJD,OBJD, v2,(long long)N_*OBJD,OBJD, N_, OBJD, N_, nullptr);
    }
    // av = relu(v2 @ wa_v)
    {
        dim3 g(H_/128, (B_*N_)/128, 1);
        gemm_f32<128,128,16,8,8,1,0,false><<<g,256,0,stream>>>(
            v2,0,OBJD, wa_v,0,H_, nullptr, nullptr,0,0, avb,0,H_, B_*N_, H_, OBJD, nullptr);
    }
    att_logits_kernel<<<(B_*N_)/4,256,0,stream>>>(avb, aqb, wa_out, attl);
    softmax_n_kernel<<<B_,128,0,stream>>>(attl, vatt);
    vemb_kernel<<<dim3(OBJD/256,B_),256,0,stream>>>(vatt, v2, vemb);
    // joint = q_repr * relu(v_emb @ wv_net + bv_net)
    {
        dim3 g(H_/64, B_/64, 1);
        gemm_f32<64,64,16,4,4,1,2,false><<<g,256,0,stream>>>(
            vemb,0,OBJD, wv_net,0,H_, bv_net, qrepr,0,H_, joint,0,H_, B_,H_,OBJD, nullptr);
    }
    // c1 = relu(joint @ wc1 + bc1)
    {
        dim3 g(2*H_/64, B_/64, 1);
        gemm_f32<64,64,16,4,4,1,0,false><<<g,256,0,stream>>>(
            joint,0,H_, wc1,0,2*H_, bc1, nullptr,0,0, c1h,0,2*H_, B_, 2*H_, H_, nullptr);
    }
    // logits = c1 @ wc2 + bc2   (N=3129 -> scalar-guarded B loads)
    {
        dim3 g((NANS_+63)/64, B_/64, 1);
        gemm_f32<64,64,16,4,4,0,0,false><<<g,256,0,stream>>>(
            c1h,0,2*H_, wc2,0,NANS_, bc2, nullptr,0,0, out,0,NANS_, B_, NANS_, 2*H_, nullptr);
    }
}

// Round 3
// 3683.104 us; speedup vs baseline: 1.7017x; 1.7017x over previous
//
#include <hip/hip_runtime.h>
#include <math.h>

#define B_    256
#define N_    100
#define OBJD  2048
#define L_    14
#define EMBD  300
#define H_    1024
#define H3    3072
#define NANS_ 3129

typedef unsigned short u16;
typedef unsigned int   u32;
typedef __attribute__((ext_vector_type(8))) short    s16x8;
typedef __attribute__((ext_vector_type(8))) u16      u16x8;
typedef __attribute__((ext_vector_type(4))) float    f32x4;

// ---------------------------------------------------------------- generic fp32 GEMM (small/medium ops)
template<int BM,int BN,int BK,int TM,int TN,int ACT,int EPI,bool GATHER>
__global__ __launch_bounds__(256)
void gemm_f32(const float* __restrict__ A, long long sA, int lda,
              const float* __restrict__ Bm, long long sB, int ldb,
              const float* __restrict__ bias,
              const float* __restrict__ src, long long sSrc, int ldsrc,
              float* __restrict__ C, long long sC, int ldc,
              int M, int N, int K, const int* __restrict__ gidx)
{
    static_assert((BM*BK)%1024==0 && (BK*BN)%1024==0 && (BM/TM)*(BN/TN)==256, "cfg");
    constexpr int AV = (BM*BK)/1024, BV = (BK*BN)/1024;
    __shared__ float As[BK][BM+4];
    __shared__ float Bs[BK][BN+4];
    const int bz = blockIdx.z;
    A  += (long long)bz * sA;
    Bm += (long long)bz * sB;
    C  += (long long)bz * sC;
    if (EPI) src += (long long)bz * sSrc;

    const int tid = threadIdx.x;
    const int m0 = blockIdx.y * BM, n0 = blockIdx.x * BN;
    const int tx = tid % (BN/TN), ty = tid / (BN/TN);
    const bool bvec = ((ldb & 3) == 0);

    float acc[TM][TN];
#pragma unroll
    for (int i=0;i<TM;i++)
#pragma unroll
      for (int j=0;j<TN;j++) acc[i][j] = 0.f;

    for (int k0 = 0; k0 < K; k0 += BK) {
#pragma unroll
        for (int u=0; u<AV; u++) {
            const int flat = (tid + u*256) * 4;
            const int r = flat / BK, c = flat % BK;
            const int gr = m0 + r, gk = k0 + c;
            float4 a4 = make_float4(0.f,0.f,0.f,0.f);
            if (gr < M) {
                const float* arow = GATHER ? (A + (long long)gidx[gr]*lda)
                                           : (A + (long long)gr*lda);
                if (gk + 3 < K) a4 = *(const float4*)(arow + gk);
                else {
                    float t0[4] = {0.f,0.f,0.f,0.f};
#pragma unroll
                    for (int i=0;i<4;i++) if (gk+i < K) t0[i] = arow[gk+i];
                    a4 = make_float4(t0[0],t0[1],t0[2],t0[3]);
                }
            }
            As[c+0][r]=a4.x; As[c+1][r]=a4.y; As[c+2][r]=a4.z; As[c+3][r]=a4.w;
        }
#pragma unroll
        for (int u=0; u<BV; u++) {
            const int flat = (tid + u*256) * 4;
            const int r = flat / BN, c = flat % BN;
            const int gk = k0 + r, gc = n0 + c;
            float4 b4 = make_float4(0.f,0.f,0.f,0.f);
            if (gk < K) {
                const float* brow = Bm + (long long)gk * ldb;
                if (bvec && (gc + 3 < N)) b4 = *(const float4*)(brow + gc);
                else {
                    float t0[4] = {0.f,0.f,0.f,0.f};
#pragma unroll
                    for (int i=0;i<4;i++) if (gc+i < N) t0[i] = brow[gc+i];
                    b4 = make_float4(t0[0],t0[1],t0[2],t0[3]);
                }
            }
            Bs[r][c+0]=b4.x; Bs[r][c+1]=b4.y; Bs[r][c+2]=b4.z; Bs[r][c+3]=b4.w;
        }
        __syncthreads();
#pragma unroll
        for (int kk=0;kk<BK;kk++) {
            float a[TM], b[TN];
#pragma unroll
            for (int p=0;p<TM/4;p++) {
                float4 t4 = *(const float4*)&As[kk][ty*TM + 4*p];
                a[4*p]=t4.x; a[4*p+1]=t4.y; a[4*p+2]=t4.z; a[4*p+3]=t4.w;
            }
#pragma unroll
            for (int p=0;p<TN/4;p++) {
                float4 t4 = *(const float4*)&Bs[kk][tx*TN + 4*p];
                b[4*p]=t4.x; b[4*p+1]=t4.y; b[4*p+2]=t4.z; b[4*p+3]=t4.w;
            }
#pragma unroll
            for (int i=0;i<TM;i++)
#pragma unroll
                for (int j=0;j<TN;j++) acc[i][j] = fmaf(a[i], b[j], acc[i][j]);
        }
        __syncthreads();
    }
#pragma unroll
    for (int i=0;i<TM;i++) {
        const int r = m0 + ty*TM + i;
        if (r >= M) continue;
#pragma unroll
        for (int j=0;j<TN;j++) {
            const int c = n0 + tx*TN + j;
            if (c >= N) continue;
            float val = acc[i][j];
            if (bias) val += bias[c];
            if (ACT == 1) val = fmaxf(val, 0.f);
            else if (ACT == 2) val = tanhf(val);
            if (EPI == 1) val += src[(long long)r*ldsrc + c];
            else if (EPI == 2) val *= src[(long long)r*ldsrc + c];
            C[(long long)r*ldc + c] = val;
        }
    }
}

// ---------------------------------------------------------------- weight split+transpose: W[K][N] -> T{hi,lo}[N][K] bf16
__global__ __launch_bounds__(256)
void split_transpose_w(const float* __restrict__ W, u16* __restrict__ Thi,
                       u16* __restrict__ Tlo, int K, int N)
{
    __shared__ float tile[64][33];
    const int k0 = blockIdx.x*64, n0 = blockIdx.y*32;
    const int t = threadIdx.x;
    const int ln = t & 31, lk = t >> 5;
#pragma unroll
    for (int i=0;i<8;i++)
        tile[lk + i*8][ln] = W[(long long)(k0 + lk + i*8)*N + n0 + ln];
    __syncthreads();
    const int wn = t >> 3, wk = (t & 7) * 8;
    u16x8 hv, lv;
#pragma unroll
    for (int i=0;i<8;i++){
        const float x = tile[wk + i][wn];
        const u32 u = __float_as_uint(x);
        hv[i] = (u16)(u >> 16);
        const float r = x - __uint_as_float(u & 0xffff0000u);
        lv[i] = (u16)(__float_as_uint(r) >> 16);
    }
    *(u16x8*)&Thi[(long long)(n0+wn)*K + k0 + wk] = hv;
    *(u16x8*)&Tlo[(long long)(n0+wn)*K + k0 + wk] = lv;
}

// ---------------------------------------------------------------- bf16x3 MFMA GEMM
// C[M,N] = act(A[M,K]_f32 @ B[K,N])  with B pre-split/transposed: BT{hi,lo}[N][K] bf16.
// A split to hi/lo bf16 on the fly during LDS staging (truncation split).
// Requires: M%256==0, N%128==0, K%32==0.  ACT: 1 relu, 2 tanh(fast).
template<int ACT>
__global__ __launch_bounds__(256, 2)
void gemm_bf16x3(const float* __restrict__ A, int lda,
                 const u16* __restrict__ BThi, const u16* __restrict__ BTlo,
                 float* __restrict__ C, int ldc, int K)
{
    constexpr int BM=256, BN=128, BK=32, PK=40;   // PK: padded LDS row (u16s)
    __shared__ __align__(16) u16 Ahi[BM*PK];
    __shared__ __align__(16) u16 Alo[BM*PK];
    __shared__ __align__(16) u16 Bhi[BN*PK];
    __shared__ __align__(16) u16 Blo[BN*PK];

    const int tid  = threadIdx.x;
    const int m0   = blockIdx.y*BM, n0 = blockIdx.x*BN;
    const int wave = tid >> 6, lane = tid & 63;
    const int wm   = wave >> 1, wn = wave & 1;
    const int r16  = lane & 15, g = lane >> 4;

    f32x4 acc[8][4];
#pragma unroll
    for (int i=0;i<8;i++)
#pragma unroll
      for (int j=0;j<4;j++) acc[i][j] = f32x4{0.f,0.f,0.f,0.f};

    const float* Arow   = A + (long long)(m0 + tid)*lda;
    const u16*   BrowH  = BThi + (long long)(n0 + (tid>>1))*K + (tid&1)*16;
    const u16*   BrowL  = BTlo + (long long)(n0 + (tid>>1))*K + (tid&1)*16;
    u16* AhiW = &Ahi[tid*PK];
    u16* AloW = &Alo[tid*PK];
    u16* BhiW = &Bhi[(tid>>1)*PK + (tid&1)*16];
    u16* BloW = &Blo[(tid>>1)*PK + (tid&1)*16];

    for (int k0 = 0; k0 < K; k0 += BK) {
        __syncthreads();                       // previous compute done
        // ---- stage A: 32 fp32 -> hi/lo bf16 (truncation split)
        const float4* src = (const float4*)(Arow + k0);
#pragma unroll
        for (int cc=0; cc<4; cc++) {
            u16x8 hv, lv;
#pragma unroll
            for (int j=0;j<2;j++) {
                const float4 f = src[cc*2+j];
                const float fa[4] = {f.x, f.y, f.z, f.w};
#pragma unroll
                for (int e=0;e<4;e++) {
                    const u32 u = __float_as_uint(fa[e]);
                    hv[j*4+e] = (u16)(u >> 16);
                    const float r = fa[e] - __uint_as_float(u & 0xffff0000u);
                    lv[j*4+e] = (u16)(__float_as_uint(r) >> 16);
                }
            }
            *(u16x8*)(AhiW + cc*8) = hv;
            *(u16x8*)(AloW + cc*8) = lv;
        }
        // ---- stage B: pre-split bf16, straight copy
        {
            const u16x8 h0 = *(const u16x8*)(BrowH + k0);
            const u16x8 h1 = *(const u16x8*)(BrowH + k0 + 8);
            const u16x8 l0 = *(const u16x8*)(BrowL + k0);
            const u16x8 l1 = *(const u16x8*)(BrowL + k0 + 8);
            *(u16x8*)(BhiW)     = h0;
            *(u16x8*)(BhiW + 8) = h1;
            *(u16x8*)(BloW)     = l0;
            *(u16x8*)(BloW + 8) = l1;
        }
        __syncthreads();
        // ---- compute: wave tile 128x64 = 8x4 frags of 16x16, 3 MFMA each
        s16x8 bh[4], bl[4];
#pragma unroll
        for (int nf=0; nf<4; nf++) {
            bh[nf] = *(const s16x8*)&Bhi[(wn*64 + nf*16 + r16)*PK + g*8];
            bl[nf] = *(const s16x8*)&Blo[(wn*64 + nf*16 + r16)*PK + g*8];
        }
#pragma unroll
        for (int mf=0; mf<8; mf++) {
            const s16x8 ah = *(const s16x8*)&Ahi[(wm*128 + mf*16 + r16)*PK + g*8];
            const s16x8 al = *(const s16x8*)&Alo[(wm*128 + mf*16 + r16)*PK + g*8];
#pragma unroll
            for (int nf=0; nf<4; nf++) {
                acc[mf][nf] = __builtin_amdgcn_mfma_f32_16x16x32_bf16(ah, bh[nf], acc[mf][nf], 0,0,0);
                acc[mf][nf] = __builtin_amdgcn_mfma_f32_16x16x32_bf16(ah, bl[nf], acc[mf][nf], 0,0,0);
                acc[mf][nf] = __builtin_amdgcn_mfma_f32_16x16x32_bf16(al, bh[nf], acc[mf][nf], 0,0,0);
            }
        }
    }
    // ---- epilogue: C/D layout col=lane&15, row=(lane>>4)*4+reg
#pragma unroll
    for (int mf=0; mf<8; mf++) {
        const int rbase = m0 + wm*128 + mf*16 + g*4;
#pragma unroll
        for (int nf=0; nf<4; nf++) {
            const int c = n0 + wn*64 + nf*16 + r16;
#pragma unroll
            for (int i=0;i<4;i++) {
                float val = acc[mf][nf][i];
                if (ACT == 1) val = fmaxf(val, 0.f);
                else if (ACT == 2) {
                    const float e = __expf(2.f*val);
                    val = 1.f - 2.f*__builtin_amdgcn_rcpf(e + 1.f);
                }
                C[(long long)(rbase+i)*ldc + c] = val;
            }
        }
    }
}

// ---------------------------------------------------------------- GRU gate math
__global__ __launch_bounds__(256)
void gru_gate_kernel(const float* __restrict__ gi, int t,
                     const float* __restrict__ gh,
                     const float* __restrict__ bhh,
                     const float* __restrict__ hIn, float* __restrict__ hOut)
{
    const int idx = blockIdx.x*256 + threadIdx.x;
    const int b = idx >> 10, j = idx & (H_-1);
    const float* gib = gi + ((long long)b*L_ + t)*H3;
    const float ir = gib[j], iz = gib[j+H_], inn = gib[j+2*H_];
    float hr, hz, hn;
    if (gh) { const float* ghb = gh + (long long)b*H3; hr=ghb[j]; hz=ghb[j+H_]; hn=ghb[j+2*H_]; }
    else    { hr=bhh[j]; hz=bhh[j+H_]; hn=bhh[j+2*H_]; }
    const float r = 1.f/(1.f+expf(-(ir+hr)));
    const float z = 1.f/(1.f+expf(-(iz+hz)));
    const float n = tanhf(inn + r*hn);
    hOut[idx] = (1.f - z)*n + z*hIn[idx];
}

// ---------------------------------------------------------------- s_proj = tanh(b4 @ ws_b)
__global__ __launch_bounds__(256)
void sproj_kernel(const float* __restrict__ bIn, const float* __restrict__ wsB,
                  float* __restrict__ sProj)
{
    const int row = blockIdx.x;
    const float* br = bIn + (long long)row * 6;
    const float b0=br[0], b1=br[1], b2=br[2], b3=br[3];
    for (int h = threadIdx.x; h < H_; h += 256) {
        float val = b0*wsB[h] + b1*wsB[H_+h] + b2*wsB[2*H_+h] + b3*wsB[3*H_+h];
        sProj[(long long)row*H_ + h] = tanhf(val);
    }
}

// ---------------------------------------------------------------- fused Gram: s_rel + v_rel
__global__ __launch_bounds__(256)
void gram_rel_kernel(const float* __restrict__ sProj, const float* __restrict__ sQ,
                     const float* __restrict__ vProj, const float* __restrict__ vQ,
                     float* __restrict__ rel)
{
    __shared__ float As[16][68];
    __shared__ float Bs[16][68];
    const int b = blockIdx.z;
    const int n0 = blockIdx.y * 64, m0 = blockIdx.x * 64;
    const int tid = threadIdx.x;
    const int lr = tid / 4, lk = (tid % 4) * 4;
    const int tx = tid % 16, ty = tid / 16;
    float acc[4][4];
#pragma unroll
    for (int i=0;i<4;i++)
#pragma unroll
      for (int j=0;j<4;j++) acc[i][j]=0.f;

    for (int pass=0; pass<2; ++pass) {
        const float* P  = pass ? vProj : sProj;
        const float* Q  = (pass ? vQ : sQ) + (long long)b * H_;
        const float* Pb = P + (long long)b * N_ * H_;
        for (int k0=0; k0<H_; k0+=16) {
            const float4 qv = *(const float4*)(Q + k0 + lk);
            float4 a4 = make_float4(0,0,0,0), b4 = make_float4(0,0,0,0);
            if (n0 + lr < N_) a4 = *(const float4*)(Pb + (long long)(n0+lr)*H_ + k0 + lk);
            if (m0 + lr < N_) b4 = *(const float4*)(Pb + (long long)(m0+lr)*H_ + k0 + lk);
            As[lk+0][lr]=a4.x*qv.x; As[lk+1][lr]=a4.y*qv.y; As[lk+2][lr]=a4.z*qv.z; As[lk+3][lr]=a4.w*qv.w;
            Bs[lk+0][lr]=b4.x; Bs[lk+1][lr]=b4.y; Bs[lk+2][lr]=b4.z; Bs[lk+3][lr]=b4.w;
            __syncthreads();
#pragma unroll
            for (int kk=0;kk<16;kk++){
                const float4 av4 = *(const float4*)&As[kk][ty*4];
                const float4 bv4 = *(const float4*)&Bs[kk][tx*4];
                const float a[4]={av4.x,av4.y,av4.z,av4.w};
                const float bb[4]={bv4.x,bv4.y,bv4.z,bv4.w};
#pragma unroll
                for (int i=0;i<4;i++)
#pragma unroll
                  for (int j=0;j<4;j++) acc[i][j] = fmaf(a[i],bb[j],acc[i][j]);
            }
            __syncthreads();
        }
    }
#pragma unroll
    for (int i=0;i<4;i++){
        const int n = n0 + ty*4 + i; if (n>=N_) continue;
#pragma unroll
        for (int j=0;j<4;j++){
            const int m = m0 + tx*4 + j; if (m>=N_) continue;
            rel[((long long)b*N_ + n)*N_ + m] = acc[i][j];
        }
    }
}

// ---------------------------------------------------------------- softmax over m
__global__ __launch_bounds__(256)
void softmax_m_kernel(float* __restrict__ rel)
{
    const int w = threadIdx.x >> 6, l = threadIdx.x & 63;
    float* r = rel + ((long long)blockIdx.x*4 + w)*N_;
    const float v0 = r[l];
    const float v1 = (l + 64 < N_) ? r[l+64] : -INFINITY;
    float mx = fmaxf(v0, v1);
    for (int s=32;s;s>>=1) mx = fmaxf(mx, __shfl_xor(mx, s));
    const float e0 = expf(v0-mx);
    const float e1 = (l+64<N_) ? expf(v1-mx) : 0.f;
    float sum = e0+e1;
    for (int s=32;s;s>>=1) sum += __shfl_xor(sum, s);
    const float inv = 1.f/sum;
    r[l] = e0*inv;
    if (l+64 < N_) r[l+64] = e1*inv;
}

// ---------------------------------------------------------------- att logits
__global__ __launch_bounds__(256)
void att_logits_kernel(const float* __restrict__ av, const float* __restrict__ aq,
                       const float* __restrict__ waOut, float* __restrict__ out)
{
    const int w = threadIdx.x >> 6, l = threadIdx.x & 63;
    const int row = blockIdx.x*4 + w;
    const int b = row / N_;
    const float* avr = av + (long long)row*H_;
    const float* aqr = aq + (long long)b*H_;
    float acc = 0.f;
#pragma unroll
    for (int i=0;i<4;i++){
        const int h = i*256 + l*4;
        const float4 a4 = *(const float4*)(avr+h);
        const float4 q4 = *(const float4*)(aqr+h);
        const float4 w4 = *(const float4*)(waOut+h);
        acc += a4.x*q4.x*w4.x + a4.y*q4.y*w4.y + a4.z*q4.z*w4.z + a4.w*q4.w*w4.w;
    }
    for (int s=32;s;s>>=1) acc += __shfl_xor(acc, s);
    if (l==0) out[row] = acc;
}

// ---------------------------------------------------------------- softmax over n
__global__ __launch_bounds__(128)
void softmax_n_kernel(const float* __restrict__ lg, float* __restrict__ att)
{
    __shared__ float s[128];
    const int b = blockIdx.x, t = threadIdx.x;
    const float v = (t < N_) ? lg[(long long)b*N_+t] : -INFINITY;
    s[t]=v; __syncthreads();
    for (int st=64;st;st>>=1){ if (t<st) s[t]=fmaxf(s[t],s[t+st]); __syncthreads(); }
    const float mx = s[0]; __syncthreads();
    const float e = (t<N_)? expf(v-mx) : 0.f;
    s[t]=e; __syncthreads();
    for (int st=64;st;st>>=1){ if (t<st) s[t]+=s[t+st]; __syncthreads(); }
    const float inv = 1.f/s[0];
    if (t<N_) att[(long long)b*N_+t] = e*inv;
}

// ---------------------------------------------------------------- v_emb
__global__ __launch_bounds__(256)
void vemb_kernel(const float* __restrict__ att, const float* __restrict__ v2,
                 float* __restrict__ vEmb)
{
    __shared__ float sa[N_];
    const int b = blockIdx.y, dt = blockIdx.x, tid = threadIdx.x;
    if (tid < N_) sa[tid] = att[(long long)b*N_+tid];
    __syncthreads();
    const int d = dt*256 + tid;
    const float* vb = v2 + (long long)b*N_*OBJD + d;
    float acc = 0.f;
#pragma unroll 4
    for (int n=0;n<N_;n++) acc += sa[n]*vb[(long long)n*OBJD];
    vEmb[(long long)b*OBJD + d] = acc;
}

// ================================================================ launcher
extern "C" void kernel_launch(void* const* d_in, const int* in_sizes, int n_in,
                              void* d_out, int out_size, void* d_ws, size_t ws_size,
                              hipStream_t stream)
{
    const float* v      = (const float*)d_in[0];
    const float* bbox   = (const float*)d_in[1];
    const int*   q      = (const int*)  d_in[3];
    const float* emb    = (const float*)d_in[5];
    const float* wih    = (const float*)d_in[6];
    const float* whh    = (const float*)d_in[7];
    const float* bih    = (const float*)d_in[8];
    const float* bhh    = (const float*)d_in[9];
    const float* wq_net = (const float*)d_in[10];
    const float* bq_net = (const float*)d_in[11];
    const float* ws_b   = (const float*)d_in[12];
    const float* ws_q   = (const float*)d_in[13];
    const float* wv_v   = (const float*)d_in[14];
    const float* wv_q   = (const float*)d_in[15];
    const float* wa_v   = (const float*)d_in[16];
    const float* wa_q   = (const float*)d_in[17];
    const float* wa_out = (const float*)d_in[18];
    const float* wv_net = (const float*)d_in[19];
    const float* bv_net = (const float*)d_in[20];
    const float* wc1    = (const float*)d_in[21];
    const float* bc1    = (const float*)d_in[22];
    const float* wc2    = (const float*)d_in[23];
    const float* bc2    = (const float*)d_in[24];
    float* out = (float*)d_out;
    (void)in_sizes; (void)n_in; (void)out_size; (void)ws_size;

    float* ws = (float*)d_ws;
    size_t off = 0;
    auto alloc = [&](size_t n){ float* p = ws + off; off += (n + 63) & ~(size_t)63; return p; };
    float* gi    = alloc((size_t)B_*L_*H3);
    float* h_a   = alloc((size_t)B_*H_);
    float* h_b   = alloc((size_t)B_*H_);
    float* gh    = alloc((size_t)B_*H3);
    float* qrepr = alloc((size_t)B_*H_);
    float* sq    = alloc((size_t)B_*H_);
    float* vqb   = alloc((size_t)B_*H_);
    float* aqb   = alloc((size_t)B_*H_);
    float* sproj = alloc((size_t)B_*N_*H_);
    float* vproj = alloc((size_t)B_*N_*H_);
    float* relb  = alloc((size_t)B_*N_*N_);
    float* v2    = alloc((size_t)B_*N_*OBJD);
    float* avb   = sproj;                          // reuse
    float* attl  = alloc((size_t)B_*N_);
    float* vatt  = alloc((size_t)B_*N_);
    float* vemb  = alloc((size_t)B_*OBJD);
    float* joint = alloc((size_t)B_*H_);
    float* c1h   = alloc((size_t)B_*2*H_);
    // bf16 split+transposed weights (u16 stored in float-granular ws)
    u16* wvvThi = (u16*)alloc((size_t)OBJD*H_/2);
    u16* wvvTlo = (u16*)alloc((size_t)OBJD*H_/2);
    u16* wavThi = (u16*)alloc((size_t)OBJD*H_/2);
    u16* wavTlo = (u16*)alloc((size_t)OBJD*H_/2);

    hipMemsetAsync(h_a, 0, (size_t)B_*H_*sizeof(float), stream);

    // weight prep for the two MFMA GEMMs
    {
        dim3 g(OBJD/64, H_/32, 1);
        split_transpose_w<<<g,256,0,stream>>>(wv_v, wvvThi, wvvTlo, OBJD, H_);
        split_transpose_w<<<g,256,0,stream>>>(wa_v, wavThi, wavTlo, OBJD, H_);
    }
    // gi = emb[q] @ wih + bih
    {
        dim3 g(H3/128, (B_*L_+127)/128, 1);
        gemm_f32<128,128,16,8,8,0,0,true><<<g,256,0,stream>>>(
            emb,0,EMBD, wih,0,H3, bih, nullptr,0,0, gi,0,H3, B_*L_, H3, EMBD, q);
    }
    // GRU
    float* hin = h_a; float* hout = h_b;
    for (int t=0;t<L_;t++){
        const float* ghp = nullptr;
        if (t>0){
            dim3 g(H3/64, B_/64, 1);
            gemm_f32<64,64,16,4,4,0,0,false><<<g,256,0,stream>>>(
                hin,0,H_, whh,0,H3, bhh, nullptr,0,0, gh,0,H3, B_, H3, H_, nullptr);
            ghp = gh;
        }
        gru_gate_kernel<<<(B_*H_)/256,256,0,stream>>>(gi, t, ghp, bhh, hin, hout);
        float* tmp=hin; hin=hout; hout=tmp;
    }
    const float* qemb = hin;

    // q-side projections
    {
        dim3 g(H_/64, B_/64, 1);
        gemm_f32<64,64,16,4,4,1,0,false><<<g,256,0,stream>>>(qemb,0,H_, wq_net,0,H_, bq_net, nullptr,0,0, qrepr,0,H_, B_,H_,H_, nullptr);
        gemm_f32<64,64,16,4,4,2,0,false><<<g,256,0,stream>>>(qemb,0,H_, ws_q,0,H_, nullptr, nullptr,0,0, sq,0,H_, B_,H_,H_, nullptr);
        gemm_f32<64,64,16,4,4,2,0,false><<<g,256,0,stream>>>(qemb,0,H_, wv_q,0,H_, nullptr, nullptr,0,0, vqb,0,H_, B_,H_,H_, nullptr);
        gemm_f32<64,64,16,4,4,1,0,false><<<g,256,0,stream>>>(qemb,0,H_, wa_q,0,H_, nullptr, nullptr,0,0, aqb,0,H_, B_,H_,H_, nullptr);
    }
    sproj_kernel<<<B_*N_,256,0,stream>>>(bbox, ws_b, sproj);
    // v_proj = tanh(v @ wv_v)    [MFMA bf16x3]
    {
        dim3 g(H_/128, (B_*N_)/256, 1);
        gemm_bf16x3<2><<<g,256,0,stream>>>(v, OBJD, wvvThi, wvvTlo, vproj, H_, OBJD);
    }
    // rel logits
    {
        dim3 g(2,2,B_);
        gram_rel_kernel<<<g,256,0,stream>>>(sproj, sq, vproj, vqb, relb);
    }
    softmax_m_kernel<<<(B_*N_)/4,256,0,stream>>>(relb);
    // v2 = rel @ v + v
    {
        dim3 g(OBJD/64, (N_+63)/64, B_);
        gemm_f32<64,64,16,4,4,0,1,false><<<g,256,0,stream>>>(
            relb,(long long)N_*N_,N_, v,(long long)N_*OBJD,OBJD, nullptr,
            v,(long long)N_*OBJD,OBJD, v2,(long long)N_*OBJD,OBJD, N_, OBJD, N_, nullptr);
    }
    // av = relu(v2 @ wa_v)       [MFMA bf16x3]
    {
        dim3 g(H_/128, (B_*N_)/256, 1);
        gemm_bf16x3<1><<<g,256,0,stream>>>(v2, OBJD, wavThi, wavTlo, avb, H_, OBJD);
    }
    att_logits_kernel<<<(B_*N_)/4,256,0,stream>>>(avb, aqb, wa_out, attl);
    softmax_n_kernel<<<B_,128,0,stream>>>(attl, vatt);
    vemb_kernel<<<dim3(OBJD/256,B_),256,0,stream>>>(vatt, v2, vemb);
    // joint
    {
        dim3 g(H_/64, B_/64, 1);
        gemm_f32<64,64,16,4,4,1,2,false><<<g,256,0,stream>>>(
            vemb,0,OBJD, wv_net,0,H_, bv_net, qrepr,0,H_, joint,0,H_, B_,H_,OBJD, nullptr);
    }
    // c1
    {
        dim3 g(2*H_/64, B_/64, 1);
        gemm_f32<64,64,16,4,4,1,0,false><<<g,256,0,stream>>>(
            joint,0,H_, wc1,0,2*H_, bc1, nullptr,0,0, c1h,0,2*H_, B_, 2*H_, H_, nullptr);
    }
    // logits
    {
        dim3 g((NANS_+63)/64, B_/64, 1);
        gemm_f32<64,64,16,4,4,0,0,false><<<g,256,0,stream>>>(
            c1h,0,2*H_, wc2,0,NANS_, bc2, nullptr,0,0, out,0,NANS_, B_, NANS_, 2*H_, nullptr);
    }
}

// Round 6
// 2985.779 us; speedup vs baseline: 2.0991x; 1.2335x over previous
//
#include <hip/hip_runtime.h>
#include <math.h>

#define B_    256
#define N_    100
#define OBJD  2048
#define L_    14
#define EMBD  300
#define H_    1024
#define H3    3072
#define NANS_ 3129

typedef unsigned short u16;
typedef unsigned int   u32;
typedef long long      ll;
typedef __attribute__((ext_vector_type(8))) short    s16x8;
typedef __attribute__((ext_vector_type(8))) u16      u16x8;
typedef __attribute__((ext_vector_type(4))) float    f32x4;

__device__ __forceinline__ void split2(float x, u16& h, u16& l) {
    const u32 u = __float_as_uint(x);
    h = (u16)(u >> 16);
    const float r = x - __uint_as_float(u & 0xffff0000u);
    l = (u16)(__float_as_uint(r) >> 16);
}
__device__ __forceinline__ float b2f(u16 v) { return __uint_as_float(((u32)v) << 16); }
__device__ __forceinline__ float tanh_fast(float v) {
    const float e = __expf(2.f * v);
    return 1.f - 2.f * __builtin_amdgcn_rcpf(e + 1.f);
}

// ---------------------------------------------------------------- generic fp32 GEMM (gi gather + v2 batched)
// ACT: 0 none. EPI: 0 none, 1 add src, 3 add src then write ONLY bf16 split (Chi/Clo).
template<int BM,int BN,int BK,int TM,int TN,int ACT,int EPI,bool GATHER>
__global__ __launch_bounds__(256)
void gemm_f32(const float* __restrict__ A, long long sA, int lda,
              const float* __restrict__ Bm, long long sB, int ldb,
              const float* __restrict__ bias,
              const float* __restrict__ src, long long sSrc, int ldsrc,
              float* __restrict__ C, u16* __restrict__ Chi, u16* __restrict__ Clo,
              long long sC, int ldc,
              int M, int N, int K, const int* __restrict__ gidx)
{
    static_assert((BM*BK)%1024==0 && (BK*BN)%1024==0 && (BM/TM)*(BN/TN)==256, "cfg");
    constexpr int AV = (BM*BK)/1024, BV = (BK*BN)/1024;
    __shared__ float As[BK][BM+4];
    __shared__ float Bs[BK][BN+4];
    const int bz = blockIdx.z;
    A  += (long long)bz * sA;
    Bm += (long long)bz * sB;
    if (EPI != 3) C += (long long)bz * sC;
    if (EPI) src += (long long)bz * sSrc;
    if constexpr (EPI == 3) { Chi += (long long)bz * sC; Clo += (long long)bz * sC; }

    const int tid = threadIdx.x;
    const int m0 = blockIdx.y * BM, n0 = blockIdx.x * BN;
    const int tx = tid % (BN/TN), ty = tid / (BN/TN);
    const bool bvec = ((ldb & 3) == 0);

    float acc[TM][TN];
#pragma unroll
    for (int i=0;i<TM;i++)
#pragma unroll
      for (int j=0;j<TN;j++) acc[i][j] = 0.f;

    for (int k0 = 0; k0 < K; k0 += BK) {
#pragma unroll
        for (int u=0; u<AV; u++) {
            const int flat = (tid + u*256) * 4;
            const int r = flat / BK, c = flat % BK;
            const int gr = m0 + r, gk = k0 + c;
            float4 a4 = make_float4(0.f,0.f,0.f,0.f);
            if (gr < M) {
                const float* arow = GATHER ? (A + (long long)gidx[gr]*lda)
                                           : (A + (long long)gr*lda);
                if (gk + 3 < K) a4 = *(const float4*)(arow + gk);
                else {
                    float t0[4] = {0.f,0.f,0.f,0.f};
#pragma unroll
                    for (int i=0;i<4;i++) if (gk+i < K) t0[i] = arow[gk+i];
                    a4 = make_float4(t0[0],t0[1],t0[2],t0[3]);
                }
            }
            As[c+0][r]=a4.x; As[c+1][r]=a4.y; As[c+2][r]=a4.z; As[c+3][r]=a4.w;
        }
#pragma unroll
        for (int u=0; u<BV; u++) {
            const int flat = (tid + u*256) * 4;
            const int r = flat / BN, c = flat % BN;
            const int gk = k0 + r, gc = n0 + c;
            float4 b4 = make_float4(0.f,0.f,0.f,0.f);
            if (gk < K) {
                const float* brow = Bm + (long long)gk * ldb;
                if (bvec && (gc + 3 < N)) b4 = *(const float4*)(brow + gc);
                else {
                    float t0[4] = {0.f,0.f,0.f,0.f};
#pragma unroll
                    for (int i=0;i<4;i++) if (gc+i < N) t0[i] = brow[gc+i];
                    b4 = make_float4(t0[0],t0[1],t0[2],t0[3]);
                }
            }
            Bs[r][c+0]=b4.x; Bs[r][c+1]=b4.y; Bs[r][c+2]=b4.z; Bs[r][c+3]=b4.w;
        }
        __syncthreads();
#pragma unroll
        for (int kk=0;kk<BK;kk++) {
            float a[TM], b[TN];
#pragma unroll
            for (int p=0;p<TM/4;p++) {
                float4 t4 = *(const float4*)&As[kk][ty*TM + 4*p];
                a[4*p]=t4.x; a[4*p+1]=t4.y; a[4*p+2]=t4.z; a[4*p+3]=t4.w;
            }
#pragma unroll
            for (int p=0;p<TN/4;p++) {
                float4 t4 = *(const float4*)&Bs[kk][tx*TN + 4*p];
                b[4*p]=t4.x; b[4*p+1]=t4.y; b[4*p+2]=t4.z; b[4*p+3]=t4.w;
            }
#pragma unroll
            for (int i=0;i<TM;i++)
#pragma unroll
                for (int j=0;j<TN;j++) acc[i][j] = fmaf(a[i], b[j], acc[i][j]);
        }
        __syncthreads();
    }
#pragma unroll
    for (int i=0;i<TM;i++) {
        const int r = m0 + ty*TM + i;
        if (r >= M) continue;
#pragma unroll
        for (int j=0;j<TN;j++) {
            const int c = n0 + tx*TN + j;
            if (c >= N) continue;
            float val = acc[i][j];
            if (bias) val += bias[c];
            if (EPI == 1 || EPI == 3) val += src[(long long)r*ldsrc + c];
            if constexpr (EPI == 3) {
                u16 h, l; split2(val, h, l);
                Chi[(long long)r*ldc + c] = h;
                Clo[(long long)r*ldc + c] = l;
            } else {
                C[(long long)r*ldc + c] = val;
            }
        }
    }
}

// ---------------------------------------------------------------- split+transpose weights: W[Kin][Nin] -> T{hi,lo}[Nout][Kld] bf16 (zero-padded)
__global__ __launch_bounds__(256)
void split_transpose_w(const float* __restrict__ W, u16* __restrict__ Thi,
                       u16* __restrict__ Tlo, int Kin, int Nin, int Kld)
{
    __shared__ float tile[64][33];
    const int k0 = blockIdx.x*64, n0 = blockIdx.y*32;
    const int t = threadIdx.x;
    const int ln = t & 31, lk = t >> 5;
#pragma unroll
    for (int i=0;i<8;i++) {
        const int k = k0 + lk + i*8, n = n0 + ln;
        tile[lk + i*8][ln] = (k < Kin && n < Nin) ? W[(long long)k*Nin + n] : 0.f;
    }
    __syncthreads();
    const int wn = t >> 3, wk = (t & 7) * 8;
    u16x8 hv, lv;
#pragma unroll
    for (int i=0;i<8;i++){
        u16 h, l; split2(tile[wk + i][wn], h, l);
        hv[i] = h; lv[i] = l;
    }
    *(u16x8*)&Thi[(long long)(n0+wn)*Kld + k0 + wk] = hv;
    *(u16x8*)&Tlo[(long long)(n0+wn)*Kld + k0 + wk] = lv;
}

// ---------------------------------------------------------------- split rows: fp32 -> hi/lo bf16 (elementwise, vectorized)
__global__ __launch_bounds__(256)
void split_rows(const float* __restrict__ x, u16* __restrict__ hi,
                u16* __restrict__ lo, long long n8)
{
    for (long long i = blockIdx.x*256 + threadIdx.x; i < n8; i += (long long)gridDim.x*256) {
        const float4 a = ((const float4*)x)[2*i];
        const float4 c = ((const float4*)x)[2*i+1];
        const float f[8] = {a.x,a.y,a.z,a.w,c.x,c.y,c.z,c.w};
        u16x8 h, l;
#pragma unroll
        for (int e=0;e<8;e++){ u16 hh,ll_; split2(f[e],hh,ll_); h[e]=hh; l[e]=ll_; }
        ((u16x8*)hi)[i] = h;
        ((u16x8*)lo)[i] = l;
    }
}

// ---------------------------------------------------------------- unified bf16x3 MFMA GEMM, pre-split A [M][K] hi/lo
// BN=128 fixed. ACT: 0 none,1 relu,2 tanh,3 per-1024-col-segment (relu,tanh,tanh,relu)
// EPI: 0 fp32 out; 1 fp32 + split out; 2 (mul src) then fp32 + split out.
template<int BM, int ACT, int EPI, bool BIAS>
__global__ __launch_bounds__(256, (BM==256)?2:3)
void gemm3s(const u16* __restrict__ Ahi, const u16* __restrict__ Alo, int lda,
            const u16* __restrict__ BThi, const u16* __restrict__ BTlo,
            const float* __restrict__ bias,
            const float* __restrict__ src, int ldsrc,
            float* __restrict__ C, u16* __restrict__ Chi, u16* __restrict__ Clo,
            int ldc, int N, int K)
{
    constexpr int BN=128, BK=32, PK=40;
    constexpr int MF = BM/32;
    __shared__ __align__(16) u16 smem[2*BM*PK + 2*BN*PK];
    u16* Ah = smem;
    u16* Al = smem + BM*PK;
    u16* Bh = smem + 2*BM*PK;
    u16* Bl = Bh + BN*PK;

    const int tid = threadIdx.x;
    const int m0 = blockIdx.y*BM, n0 = blockIdx.x*BN;
    const int wave = tid>>6, lane = tid&63;
    const int wm = wave>>1, wn = wave&1;
    const int r16 = lane&15, g = lane>>4;

    f32x4 acc[MF][4];
#pragma unroll
    for (int i=0;i<MF;i++)
#pragma unroll
      for (int j=0;j<4;j++) acc[i][j] = f32x4{0.f,0.f,0.f,0.f};

    const int ar = (BM==256) ? tid : (tid>>2);
    const int ac = (BM==256) ? 0   : ((tid&3)*8);
    const u16* pAh = Ahi + (long long)(m0+ar)*lda + ac;
    const u16* pAl = Alo + (long long)(m0+ar)*lda + ac;
    u16* sAh = Ah + ar*PK + ac;
    u16* sAl = Al + ar*PK + ac;
    const int br = tid>>1, bc = (tid&1)*16;
    const u16* pBh = BThi + (long long)(n0+br)*K + bc;
    const u16* pBl = BTlo + (long long)(n0+br)*K + bc;
    u16* sBh = Bh + br*PK + bc;
    u16* sBl = Bl + br*PK + bc;

    for (int k0=0; k0<K; k0+=BK) {
        __syncthreads();
        if constexpr (BM==256) {
#pragma unroll
            for (int u=0;u<4;u++){
                *(u16x8*)(sAh+u*8) = *(const u16x8*)(pAh + k0 + u*8);
                *(u16x8*)(sAl+u*8) = *(const u16x8*)(pAl + k0 + u*8);
            }
        } else {
            *(u16x8*)sAh = *(const u16x8*)(pAh + k0);
            *(u16x8*)sAl = *(const u16x8*)(pAl + k0);
        }
        *(u16x8*)(sBh)   = *(const u16x8*)(pBh + k0);
        *(u16x8*)(sBh+8) = *(const u16x8*)(pBh + k0 + 8);
        *(u16x8*)(sBl)   = *(const u16x8*)(pBl + k0);
        *(u16x8*)(sBl+8) = *(const u16x8*)(pBl + k0 + 8);
        __syncthreads();

        s16x8 bh[4], bl[4];
#pragma unroll
        for (int nf=0;nf<4;nf++){
            bh[nf] = *(const s16x8*)&Bh[(wn*64 + nf*16 + r16)*PK + g*8];
            bl[nf] = *(const s16x8*)&Bl[(wn*64 + nf*16 + r16)*PK + g*8];
        }
#pragma unroll
        for (int mf=0; mf<MF; mf++){
            const s16x8 ah = *(const s16x8*)&Ah[(wm*(BM/2) + mf*16 + r16)*PK + g*8];
            const s16x8 al = *(const s16x8*)&Al[(wm*(BM/2) + mf*16 + r16)*PK + g*8];
#pragma unroll
            for (int nf=0;nf<4;nf++){
                acc[mf][nf] = __builtin_amdgcn_mfma_f32_16x16x32_bf16(ah, bh[nf], acc[mf][nf], 0,0,0);
                acc[mf][nf] = __builtin_amdgcn_mfma_f32_16x16x32_bf16(ah, bl[nf], acc[mf][nf], 0,0,0);
                acc[mf][nf] = __builtin_amdgcn_mfma_f32_16x16x32_bf16(al, bh[nf], acc[mf][nf], 0,0,0);
            }
        }
    }
    // epilogue: C/D layout col=lane&15, row=(lane>>4)*4+reg
#pragma unroll
    for (int mf=0;mf<MF;mf++){
        const int rr = m0 + wm*(BM/2) + mf*16 + g*4;
#pragma unroll
        for (int nf=0;nf<4;nf++){
            const int cc = n0 + wn*64 + nf*16 + r16;
            if (cc >= N) continue;
            const float bval = BIAS ? bias[cc] : 0.f;
#pragma unroll
            for (int i=0;i<4;i++){
                float val = acc[mf][nf][i] + bval;
                if (ACT == 1) val = fmaxf(val, 0.f);
                else if (ACT == 2) val = tanh_fast(val);
                else if (ACT == 3) {
                    const int seg = cc >> 10;
                    val = (seg==0 || seg==3) ? fmaxf(val, 0.f) : tanh_fast(val);
                }
                if (EPI == 2) val *= src[(long long)(rr+i)*ldsrc + cc];
                const long long o = (long long)(rr+i)*ldc + cc;
                C[o] = val;
                if (EPI >= 1) {
                    u16 h, l; split2(val, h, l);
                    Chi[o] = h; Clo[o] = l;
                }
            }
        }
    }
}

// ---------------------------------------------------------------- fused GRU step (t>=1): gh = h@whh (bf16x3 MFMA) + gates + h-split
__global__ __launch_bounds__(192)
void gru_step(const float* __restrict__ hprev,
              const u16* __restrict__ hHi, const u16* __restrict__ hLo,
              const u16* __restrict__ whhThi, const u16* __restrict__ whhTlo,
              const float* __restrict__ gi, int t, const float* __restrict__ bhh,
              float* __restrict__ hout, u16* __restrict__ hoHi, u16* __restrict__ hoLo)
{
    constexpr int PK = 40;
    __shared__ __align__(16) u16 smem[8*32*PK];   // Ah,Al,B{h,l}x3 segments
    u16* Ah = smem;
    u16* Al = smem + 32*PK;
    const int tid = threadIdx.x, seg = tid>>6, lane = tid&63;
    u16* Bh = smem + 2*32*PK + seg*2*32*PK;
    u16* Bl = Bh + 32*PK;
    const int j0 = blockIdx.x*32, b0 = blockIdx.y*32;
    const int r16 = lane&15, g = lane>>4;
    f32x4 acc[2][2];
#pragma unroll
    for (int i=0;i<2;i++)
#pragma unroll
      for (int j=0;j<2;j++) acc[i][j] = f32x4{0.f,0.f,0.f,0.f};

    const int sr = lane>>1, sc = (lane&1)*16;
    const u16* pAh = hHi + (long long)(b0+sr)*H_ + sc;
    const u16* pAl = hLo + (long long)(b0+sr)*H_ + sc;
    const u16* pBh = whhThi + (long long)(seg*H_ + j0 + sr)*H_ + sc;
    const u16* pBl = whhTlo + (long long)(seg*H_ + j0 + sr)*H_ + sc;
    u16* sAh = Ah + sr*PK + sc;
    u16* sAl = Al + sr*PK + sc;
    u16* sBh = Bh + sr*PK + sc;
    u16* sBl = Bl + sr*PK + sc;

    for (int k0=0; k0<H_; k0+=32) {
        __syncthreads();
        if (seg == 0) {
            *(u16x8*)(sAh)   = *(const u16x8*)(pAh + k0);
            *(u16x8*)(sAh+8) = *(const u16x8*)(pAh + k0 + 8);
            *(u16x8*)(sAl)   = *(const u16x8*)(pAl + k0);
            *(u16x8*)(sAl+8) = *(const u16x8*)(pAl + k0 + 8);
        }
        *(u16x8*)(sBh)   = *(const u16x8*)(pBh + k0);
        *(u16x8*)(sBh+8) = *(const u16x8*)(pBh + k0 + 8);
        *(u16x8*)(sBl)   = *(const u16x8*)(pBl + k0);
        *(u16x8*)(sBl+8) = *(const u16x8*)(pBl + k0 + 8);
        __syncthreads();
        s16x8 bh[2], bl[2];
#pragma unroll
        for (int nf=0;nf<2;nf++){
            bh[nf] = *(const s16x8*)&Bh[(nf*16 + r16)*PK + g*8];
            bl[nf] = *(const s16x8*)&Bl[(nf*16 + r16)*PK + g*8];
        }
#pragma unroll
        for (int mf=0;mf<2;mf++){
            const s16x8 ah = *(const s16x8*)&Ah[(mf*16 + r16)*PK + g*8];
            const s16x8 al = *(const s16x8*)&Al[(mf*16 + r16)*PK + g*8];
#pragma unroll
            for (int nf=0;nf<2;nf++){
                acc[mf][nf] = __builtin_amdgcn_mfma_f32_16x16x32_bf16(ah, bh[nf], acc[mf][nf], 0,0,0);
                acc[mf][nf] = __builtin_amdgcn_mfma_f32_16x16x32_bf16(ah, bl[nf], acc[mf][nf], 0,0,0);
                acc[mf][nf] = __builtin_amdgcn_mfma_f32_16x16x32_bf16(al, bh[nf], acc[mf][nf], 0,0,0);
            }
        }
    }
    __syncthreads();
    float* ghb = (float*)smem;          // 3*32*32 floats = 12288 B <= 20480 B
#pragma unroll
    for (int mf=0;mf<2;mf++)
#pragma unroll
      for (int nf=0;nf<2;nf++)
#pragma unroll
        for (int i=0;i<4;i++)
            ghb[(seg*32 + mf*16 + g*4 + i)*32 + nf*16 + r16] = acc[mf][nf][i];
    __syncthreads();
    for (int idx = tid; idx < 1024; idx += 192) {
        const int r = idx>>5, c = idx&31;
        const int b = b0 + r, j = j0 + c;
        const float* gib = gi + ((long long)b*L_ + t)*H3 + j;
        const float ir = gib[0], iz = gib[H_], inn = gib[2*H_];
        const float hr = ghb[(0*32+r)*32+c] + bhh[j];
        const float hz = ghb[(1*32+r)*32+c] + bhh[j+H_];
        const float hn = ghb[(2*32+r)*32+c] + bhh[j+2*H_];
        const float hp = hprev[(long long)b*H_ + j];
        const float rg = 1.f/(1.f+expf(-(ir+hr)));
        const float zg = 1.f/(1.f+expf(-(iz+hz)));
        const float nn = tanhf(inn + rg*hn);
        const float ho = (1.f - zg)*nn + zg*hp;
        hout[(long long)b*H_ + j] = ho;
        u16 hh, hl; split2(ho, hh, hl);
        hoHi[(long long)b*H_ + j] = hh;
        hoLo[(long long)b*H_ + j] = hl;
    }
}

// ---------------------------------------------------------------- GRU t=0 (h=0): gates + split
__global__ __launch_bounds__(256)
void gru_t0(const float* __restrict__ gi, const float* __restrict__ bhh,
            float* __restrict__ h, u16* __restrict__ hHi, u16* __restrict__ hLo)
{
    const int idx = blockIdx.x*256 + threadIdx.x;
    const int b = idx >> 10, j = idx & (H_-1);
    const float* gib = gi + ((long long)b*L_)*H3 + j;
    const float ir = gib[0], iz = gib[H_], inn = gib[2*H_];
    const float rg = 1.f/(1.f+expf(-(ir+bhh[j])));
    const float zg = 1.f/(1.f+expf(-(iz+bhh[j+H_])));
    const float nn = tanhf(inn + rg*bhh[j+2*H_]);
    const float ho = (1.f - zg)*nn;
    h[idx] = ho;
    u16 hh, hl; split2(ho, hh, hl);
    hHi[idx] = hh; hLo[idx] = hl;
}

// ---------------------------------------------------------------- qbias = [bq_net, 0, 0, 0]
__global__ __launch_bounds__(256)
void build_qbias(const float* __restrict__ bq, float* __restrict__ qb)
{
    const int i = blockIdx.x*256 + threadIdx.x;
    if (i < 4096) qb[i] = (i < 1024) ? bq[i] : 0.f;
}

// ---------------------------------------------------------------- s_proj = tanh(b4 @ ws_b)
__global__ __launch_bounds__(256)
void sproj_kernel(const float* __restrict__ bIn, const float* __restrict__ wsB,
                  float* __restrict__ sProj)
{
    const int row = blockIdx.x;
    const float* br = bIn + (long long)row * 6;
    const float b0=br[0], b1=br[1], b2=br[2], b3=br[3];
    for (int h = threadIdx.x; h < H_; h += 256) {
        float val = b0*wsB[h] + b1*wsB[H_+h] + b2*wsB[2*H_+h] + b3*wsB[3*H_+h];
        sProj[(long long)row*H_ + h] = tanhf(val);
    }
}

// ---------------------------------------------------------------- fused Gram: s_rel + v_rel
__global__ __launch_bounds__(256)
void gram_rel_kernel(const float* __restrict__ sProj, const float* __restrict__ sQ,
                     const float* __restrict__ vProj, const float* __restrict__ vQ,
                     int ldq, float* __restrict__ rel)
{
    __shared__ float As[16][68];
    __shared__ float Bs[16][68];
    const int b = blockIdx.z;
    const int n0 = blockIdx.y * 64, m0 = blockIdx.x * 64;
    const int tid = threadIdx.x;
    const int lr = tid / 4, lk = (tid % 4) * 4;
    const int tx = tid % 16, ty = tid / 16;
    float acc[4][4];
#pragma unroll
    for (int i=0;i<4;i++)
#pragma unroll
      for (int j=0;j<4;j++) acc[i][j]=0.f;

    for (int pass=0; pass<2; ++pass) {
        const float* P  = pass ? vProj : sProj;
        const float* Q  = (pass ? vQ : sQ) + (long long)b * ldq;
        const float* Pb = P + (long long)b * N_ * H_;
        for (int k0=0; k0<H_; k0+=16) {
            const float4 qv = *(const float4*)(Q + k0 + lk);
            float4 a4 = make_float4(0,0,0,0), b4 = make_float4(0,0,0,0);
            if (n0 + lr < N_) a4 = *(const float4*)(Pb + (long long)(n0+lr)*H_ + k0 + lk);
            if (m0 + lr < N_) b4 = *(const float4*)(Pb + (long long)(m0+lr)*H_ + k0 + lk);
            As[lk+0][lr]=a4.x*qv.x; As[lk+1][lr]=a4.y*qv.y; As[lk+2][lr]=a4.z*qv.z; As[lk+3][lr]=a4.w*qv.w;
            Bs[lk+0][lr]=b4.x; Bs[lk+1][lr]=b4.y; Bs[lk+2][lr]=b4.z; Bs[lk+3][lr]=b4.w;
            __syncthreads();
#pragma unroll
            for (int kk=0;kk<16;kk++){
                const float4 av4 = *(const float4*)&As[kk][ty*4];
                const float4 bv4 = *(const float4*)&Bs[kk][tx*4];
                const float a[4]={av4.x,av4.y,av4.z,av4.w};
                const float bb[4]={bv4.x,bv4.y,bv4.z,bv4.w};
#pragma unroll
                for (int i=0;i<4;i++)
#pragma unroll
                  for (int j=0;j<4;j++) acc[i][j] = fmaf(a[i],bb[j],acc[i][j]);
            }
            __syncthreads();
        }
    }
#pragma unroll
    for (int i=0;i<4;i++){
        const int n = n0 + ty*4 + i; if (n>=N_) continue;
#pragma unroll
        for (int j=0;j<4;j++){
            const int m = m0 + tx*4 + j; if (m>=N_) continue;
            rel[((long long)b*N_ + n)*N_ + m] = acc[i][j];
        }
    }
}

// ---------------------------------------------------------------- softmax over m
__global__ __launch_bounds__(256)
void softmax_m_kernel(float* __restrict__ rel)
{
    const int w = threadIdx.x >> 6, l = threadIdx.x & 63;
    float* r = rel + ((long long)blockIdx.x*4 + w)*N_;
    const float v0 = r[l];
    const float v1 = (l + 64 < N_) ? r[l+64] : -INFINITY;
    float mx = fmaxf(v0, v1);
    for (int s=32;s;s>>=1) mx = fmaxf(mx, __shfl_xor(mx, s));
    const float e0 = expf(v0-mx);
    const float e1 = (l+64<N_) ? expf(v1-mx) : 0.f;
    float sum = e0+e1;
    for (int s=32;s;s>>=1) sum += __shfl_xor(sum, s);
    const float inv = 1.f/sum;
    r[l] = e0*inv;
    if (l+64 < N_) r[l+64] = e1*inv;
}

// ---------------------------------------------------------------- att logits
__global__ __launch_bounds__(256)
void att_logits_kernel(const float* __restrict__ av, const float* __restrict__ aq,
                       int ldq, const float* __restrict__ waOut, float* __restrict__ out)
{
    const int w = threadIdx.x >> 6, l = threadIdx.x & 63;
    const int row = blockIdx.x*4 + w;
    const int b = row / N_;
    const float* avr = av + (long long)row*H_;
    const float* aqr = aq + (long long)b*ldq;
    float acc = 0.f;
#pragma unroll
    for (int i=0;i<4;i++){
        const int h = i*256 + l*4;
        const float4 a4 = *(const float4*)(avr+h);
        const float4 q4 = *(const float4*)(aqr+h);
        const float4 w4 = *(const float4*)(waOut+h);
        acc += a4.x*q4.x*w4.x + a4.y*q4.y*w4.y + a4.z*q4.z*w4.z + a4.w*q4.w*w4.w;
    }
    for (int s=32;s;s>>=1) acc += __shfl_xor(acc, s);
    if (l==0) out[row] = acc;
}

// ---------------------------------------------------------------- softmax over n
__global__ __launch_bounds__(128)
void softmax_n_kernel(const float* __restrict__ lg, float* __restrict__ att)
{
    __shared__ float s[128];
    const int b = blockIdx.x, t = threadIdx.x;
    const float v = (t < N_) ? lg[(long long)b*N_+t] : -INFINITY;
    s[t]=v; __syncthreads();
    for (int st=64;st;st>>=1){ if (t<st) s[t]=fmaxf(s[t],s[t+st]); __syncthreads(); }
    const float mx = s[0]; __syncthreads();
    const float e = (t<N_)? expf(v-mx) : 0.f;
    s[t]=e; __syncthreads();
    for (int st=64;st;st>>=1){ if (t<st) s[t]+=s[t+st]; __syncthreads(); }
    const float inv = 1.f/s[0];
    if (t<N_) att[(long long)b*N_+t] = e*inv;
}

// ---------------------------------------------------------------- v_emb from split v2, emit split
__global__ __launch_bounds__(256)
void vemb_kernel(const float* __restrict__ att, const u16* __restrict__ v2hi,
                 const u16* __restrict__ v2lo, u16* __restrict__ veHi,
                 u16* __restrict__ veLo)
{
    __shared__ float sa[N_];
    const int b = blockIdx.y, dt = blockIdx.x, tid = threadIdx.x;
    if (tid < N_) sa[tid] = att[(long long)b*N_+tid];
    __syncthreads();
    const int d = dt*256 + tid;
    const long long base = (long long)b*N_*OBJD + d;
    float acc = 0.f;
#pragma unroll 4
    for (int n=0;n<N_;n++) {
        const long long o = base + (long long)n*OBJD;
        acc += sa[n]*(b2f(v2hi[o]) + b2f(v2lo[o]));
    }
    u16 h, l; split2(acc, h, l);
    veHi[(long long)b*OBJD + d] = h;
    veLo[(long long)b*OBJD + d] = l;
}

// ================================================================ launcher
extern "C" void kernel_launch(void* const* d_in, const int* in_sizes, int n_in,
                              void* d_out, int out_size, void* d_ws, size_t ws_size,
                              hipStream_t stream)
{
    const float* v      = (const float*)d_in[0];
    const float* bbox   = (const float*)d_in[1];
    const int*   q      = (const int*)  d_in[3];
    const float* emb    = (const float*)d_in[5];
    const float* wih    = (const float*)d_in[6];
    const float* whh    = (const float*)d_in[7];
    const float* bih    = (const float*)d_in[8];
    const float* bhh    = (const float*)d_in[9];
    const float* wq_net = (const float*)d_in[10];
    const float* bq_net = (const float*)d_in[11];
    const float* ws_b   = (const float*)d_in[12];
    const float* ws_q   = (const float*)d_in[13];
    const float* wv_v   = (const float*)d_in[14];
    const float* wv_q   = (const float*)d_in[15];
    const float* wa_v   = (const float*)d_in[16];
    const float* wa_q   = (const float*)d_in[17];
    const float* wa_out = (const float*)d_in[18];
    const float* wv_net = (const float*)d_in[19];
    const float* bv_net = (const float*)d_in[20];
    const float* wc1    = (const float*)d_in[21];
    const float* bc1    = (const float*)d_in[22];
    const float* wc2    = (const float*)d_in[23];
    const float* bc2    = (const float*)d_in[24];
    float* out = (float*)d_out;
    (void)in_sizes; (void)n_in; (void)out_size; (void)ws_size; (void)bih;

    float* ws = (float*)d_ws;
    size_t off = 0;
    auto alloc = [&](size_t n){ float* p = ws + off; off += (n + 63) & ~(size_t)63; return p; };
    float* gi    = alloc((size_t)B_*L_*H3);
    float* h_a   = alloc((size_t)B_*H_);
    float* h_b   = alloc((size_t)B_*H_);
    u16* hhi_a = (u16*)alloc((size_t)B_*H_/2);
    u16* hlo_a = (u16*)alloc((size_t)B_*H_/2);
    u16* hhi_b = (u16*)alloc((size_t)B_*H_/2);
    u16* hlo_b = (u16*)alloc((size_t)B_*H_/2);
    float* qcat  = alloc((size_t)B_*4096);
    float* qbias = alloc(4096);
    float* sproj = alloc((size_t)B_*N_*H_);
    float* vproj = alloc((size_t)B_*N_*H_);
    float* relb  = alloc((size_t)B_*N_*N_);
    u16* vhi = (u16*)alloc((size_t)B_*N_*OBJD/2);    // later reused as v2hi
    u16* vlo = (u16*)alloc((size_t)B_*N_*OBJD/2);    // later reused as v2lo
    float* avb   = sproj;                            // reuse
    float* attl  = alloc((size_t)B_*N_);
    float* vatt  = alloc((size_t)B_*N_);
    u16* vembHi = (u16*)alloc((size_t)B_*OBJD/2);
    u16* vembLo = (u16*)alloc((size_t)B_*OBJD/2);
    float* jointf = alloc((size_t)B_*H_);
    u16* jointHi = (u16*)alloc((size_t)B_*H_/2);
    u16* jointLo = (u16*)alloc((size_t)B_*H_/2);
    float* c1f   = alloc((size_t)B_*2*H_);
    u16* c1Hi = (u16*)alloc((size_t)B_*H_);
    u16* c1Lo = (u16*)alloc((size_t)B_*H_);
    // weight splits (bf16, transposed)
    u16* whhThi = (u16*)alloc((size_t)H3*H_/2);
    u16* whhTlo = (u16*)alloc((size_t)H3*H_/2);
    u16* qcThi  = (u16*)alloc((size_t)4096*H_/2);
    u16* qcTlo  = (u16*)alloc((size_t)4096*H_/2);
    u16* wvvThi = (u16*)alloc((size_t)H_*OBJD/2);
    u16* wvvTlo = (u16*)alloc((size_t)H_*OBJD/2);
    u16* wavThi = (u16*)alloc((size_t)H_*OBJD/2);
    u16* wavTlo = (u16*)alloc((size_t)H_*OBJD/2);
    u16* wvnThi = (u16*)alloc((size_t)H_*OBJD/2);
    u16* wvnTlo = (u16*)alloc((size_t)H_*OBJD/2);
    u16* wc1Thi = (u16*)alloc((size_t)2*H_*H_/2);
    u16* wc1Tlo = (u16*)alloc((size_t)2*H_*H_/2);
    u16* wc2Thi = (u16*)alloc((size_t)3200*2*H_/2);
    u16* wc2Tlo = (u16*)alloc((size_t)3200*2*H_/2);

    // ---- weight prep (independent)
    split_transpose_w<<<dim3(H_/64, H3/32),256,0,stream>>>(whh, whhThi, whhTlo, H_, H3, H_);
    split_transpose_w<<<dim3(H_/64, H_/32),256,0,stream>>>(wq_net, qcThi + (size_t)0*H_*H_, qcTlo + (size_t)0*H_*H_, H_, H_, H_);
    split_transpose_w<<<dim3(H_/64, H_/32),256,0,stream>>>(ws_q,   qcThi + (size_t)1*H_*H_, qcTlo + (size_t)1*H_*H_, H_, H_, H_);
    split_transpose_w<<<dim3(H_/64, H_/32),256,0,stream>>>(wv_q,   qcThi + (size_t)2*H_*H_, qcTlo + (size_t)2*H_*H_, H_, H_, H_);
    split_transpose_w<<<dim3(H_/64, H_/32),256,0,stream>>>(wa_q,   qcThi + (size_t)3*H_*H_, qcTlo + (size_t)3*H_*H_, H_, H_, H_);
    split_transpose_w<<<dim3(OBJD/64, H_/32),256,0,stream>>>(wv_v, wvvThi, wvvTlo, OBJD, H_, OBJD);
    split_transpose_w<<<dim3(OBJD/64, H_/32),256,0,stream>>>(wa_v, wavThi, wavTlo, OBJD, H_, OBJD);
    split_transpose_w<<<dim3(OBJD/64, H_/32),256,0,stream>>>(wv_net, wvnThi, wvnTlo, OBJD, H_, OBJD);
    split_transpose_w<<<dim3(H_/64, 2*H_/32),256,0,stream>>>(wc1, wc1Thi, wc1Tlo, H_, 2*H_, H_);
    split_transpose_w<<<dim3(2*H_/64, 3200/32),256,0,stream>>>(wc2, wc2Thi, wc2Tlo, 2*H_, NANS_, 2*H_);
    split_rows<<<2048,256,0,stream>>>(v, vhi, vlo, (long long)B_*N_*OBJD/8);
    build_qbias<<<16,256,0,stream>>>(bq_net, qbias);

    // ---- gi = emb[q] @ wih + bih  (fp32, gather)
    {
        dim3 g(H3/128, (B_*L_+127)/128, 1);
        gemm_f32<128,128,16,8,8,0,0,true><<<g,256,0,stream>>>(
            emb,0,EMBD, wih,0,H3, bih, nullptr,0,0, gi,nullptr,nullptr,0,H3, B_*L_, H3, EMBD, q);
    }
    // ---- GRU
    gru_t0<<<(B_*H_)/256,256,0,stream>>>(gi, bhh, h_a, hhi_a, hlo_a);
    float* hp = h_a; u16* hpHi = hhi_a; u16* hpLo = hlo_a;
    float* hn = h_b; u16* hnHi = hhi_b; u16* hnLo = hlo_b;
    for (int t=1;t<L_;t++){
        gru_step<<<dim3(H_/32, B_/32),192,0,stream>>>(hp, hpHi, hpLo, whhThi, whhTlo,
                                                      gi, t, bhh, hn, hnHi, hnLo);
        float* tf=hp; hp=hn; hn=tf;
        u16* th=hpHi; hpHi=hnHi; hnHi=th;
        u16* tl=hpLo; hpLo=hnLo; hnLo=tl;
    }
    // final h split: hpHi/hpLo
    // ---- qcat = [relu(qemb@wq+bq) | tanh(qemb@ws_q) | tanh(qemb@wv_q) | relu(qemb@wa_q)]
    gemm3s<64,3,0,true><<<dim3(4096/128, B_/64),256,0,stream>>>(
        hpHi, hpLo, H_, qcThi, qcTlo, qbias, nullptr,0,
        qcat, nullptr, nullptr, 4096, 4096, H_);
    const float* qrepr = qcat;
    const float* sq    = qcat + 1024;
    const float* vq    = qcat + 2048;
    const float* aq    = qcat + 3072;

    sproj_kernel<<<B_*N_,256,0,stream>>>(bbox, ws_b, sproj);
    // ---- v_proj = tanh(v @ wv_v)
    gemm3s<256,2,0,false><<<dim3(H_/128, (B_*N_)/256),256,0,stream>>>(
        vhi, vlo, OBJD, wvvThi, wvvTlo, nullptr, nullptr,0,
        vproj, nullptr, nullptr, H_, H_, OBJD);
    // ---- rel logits + softmax
    gram_rel_kernel<<<dim3(2,2,B_),256,0,stream>>>(sproj, sq, vproj, vq, 4096, relb);
    softmax_m_kernel<<<(B_*N_)/4,256,0,stream>>>(relb);
    // ---- v2 = rel @ v + v  -> split bf16 only (vhi/vlo reused as v2hi/v2lo)
    {
        dim3 g(OBJD/64, (N_+63)/64, B_);
        gemm_f32<64,64,16,4,4,0,3,false><<<g,256,0,stream>>>(
            relb,(long long)N_*N_,N_, v,(long long)N_*OBJD,OBJD, nullptr,
            v,(long long)N_*OBJD,OBJD, nullptr, vhi, vlo,
            (long long)N_*OBJD, OBJD, N_, OBJD, N_, nullptr);
    }
    // ---- av = relu(v2 @ wa_v)
    gemm3s<256,1,0,false><<<dim3(H_/128, (B_*N_)/256),256,0,stream>>>(
        vhi, vlo, OBJD, wavThi, wavTlo, nullptr, nullptr,0,
        avb, nullptr, nullptr, H_, H_, OBJD);
    att_logits_kernel<<<(B_*N_)/4,256,0,stream>>>(avb, aq, 4096, wa_out, attl);
    softmax_n_kernel<<<B_,128,0,stream>>>(attl, vatt);
    vemb_kernel<<<dim3(OBJD/256,B_),256,0,stream>>>(vatt, vhi, vlo, vembHi, vembLo);
    // ---- joint = relu(vemb@wv_net + bv) * qrepr   (+ split for c1)
    gemm3s<64,1,2,true><<<dim3(H_/128, B_/64),256,0,stream>>>(
        vembHi, vembLo, OBJD, wvnThi, wvnTlo, bv_net, qrepr, 4096,
        jointf, jointHi, jointLo, H_, H_, OBJD);
    // ---- c1 = relu(joint@wc1 + bc1)  (+ split)
    gemm3s<64,1,1,true><<<dim3(2*H_/128, B_/64),256,0,stream>>>(
        jointHi, jointLo, H_, wc1Thi, wc1Tlo, bc1, nullptr,0,
        c1f, c1Hi, c1Lo, 2*H_, 2*H_, H_);
    // ---- logits = c1 @ wc2 + bc2   (N=3129, padded BT rows zeroed)
    gemm3s<64,0,0,true><<<dim3(3200/128, B_/64),256,0,stream>>>(
        c1Hi, c1Lo, 2*H_, wc2Thi, wc2Tlo, bc2, nullptr,0,
        out, nullptr, nullptr, NANS_, NANS_, 2*H_);
}

// Round 7
// 2691.092 us; speedup vs baseline: 2.3289x; 1.1095x over previous
//
#include <hip/hip_runtime.h>
#include <math.h>

#define B_    256
#define N_    100
#define OBJD  2048
#define L_    14
#define EMBD  300
#define H_    1024
#define H3    3072
#define NANS_ 3129

typedef unsigned short u16;
typedef unsigned int   u32;
typedef __attribute__((ext_vector_type(8))) short    s16x8;
typedef __attribute__((ext_vector_type(8))) u16      u16x8;
typedef __attribute__((ext_vector_type(4))) float    f32x4;

__device__ __forceinline__ void split2(float x, u16& h, u16& l) {
    const u32 u = __float_as_uint(x);
    h = (u16)(u >> 16);
    const float r = x - __uint_as_float(u & 0xffff0000u);
    l = (u16)(__float_as_uint(r) >> 16);
}
__device__ __forceinline__ float b2f(u16 v) { return __uint_as_float(((u32)v) << 16); }
__device__ __forceinline__ float tanh_fast(float v) {
    const float e = __expf(2.f * v);
    return 1.f - 2.f * __builtin_amdgcn_rcpf(e + 1.f);
}
// interleaved split layout: logical [M][Ncols] fp32 -> u16 [M][2*Ncols],
// per 32-col granule: [hi32 | lo32].  offset(r,c) = r*2*Nc + (c>>5)*64 + (c&31); lo at +32.

// ---------------------------------------------------------------- generic fp32 GEMM (gi gather + v2 batched)
// EPI: 0 none; 3: add src, write ONLY interleaved split to Csp.
template<int BM,int BN,int BK,int TM,int TN,int EPI,bool GATHER>
__global__ __launch_bounds__(256)
void gemm_f32(const float* __restrict__ A, long long sA, int lda,
              const float* __restrict__ Bm, long long sB, int ldb,
              const float* __restrict__ bias,
              const float* __restrict__ src, long long sSrc, int ldsrc,
              float* __restrict__ C, u16* __restrict__ Csp,
              long long sC, int ldc,
              int M, int N, int K, const int* __restrict__ gidx)
{
    static_assert((BM*BK)%1024==0 && (BK*BN)%1024==0 && (BM/TM)*(BN/TN)==256, "cfg");
    constexpr int AV = (BM*BK)/1024, BV = (BK*BN)/1024;
    __shared__ float As[BK][BM+4];
    __shared__ float Bs[BK][BN+4];
    const int bz = blockIdx.z;
    A  += (long long)bz * sA;
    Bm += (long long)bz * sB;
    if (EPI != 3) C += (long long)bz * sC;
    if (EPI) src += (long long)bz * sSrc;
    if constexpr (EPI == 3) Csp += (long long)bz * sC * 2;

    const int tid = threadIdx.x;
    const int m0 = blockIdx.y * BM, n0 = blockIdx.x * BN;
    const int tx = tid % (BN/TN), ty = tid / (BN/TN);
    const bool bvec = ((ldb & 3) == 0);

    float acc[TM][TN];
#pragma unroll
    for (int i=0;i<TM;i++)
#pragma unroll
      for (int j=0;j<TN;j++) acc[i][j] = 0.f;

    for (int k0 = 0; k0 < K; k0 += BK) {
#pragma unroll
        for (int u=0; u<AV; u++) {
            const int flat = (tid + u*256) * 4;
            const int r = flat / BK, c = flat % BK;
            const int gr = m0 + r, gk = k0 + c;
            float4 a4 = make_float4(0.f,0.f,0.f,0.f);
            if (gr < M) {
                const float* arow = GATHER ? (A + (long long)gidx[gr]*lda)
                                           : (A + (long long)gr*lda);
                if (gk + 3 < K) a4 = *(const float4*)(arow + gk);
                else {
                    float t0[4] = {0.f,0.f,0.f,0.f};
#pragma unroll
                    for (int i=0;i<4;i++) if (gk+i < K) t0[i] = arow[gk+i];
                    a4 = make_float4(t0[0],t0[1],t0[2],t0[3]);
                }
            }
            As[c+0][r]=a4.x; As[c+1][r]=a4.y; As[c+2][r]=a4.z; As[c+3][r]=a4.w;
        }
#pragma unroll
        for (int u=0; u<BV; u++) {
            const int flat = (tid + u*256) * 4;
            const int r = flat / BN, c = flat % BN;
            const int gk = k0 + r, gc = n0 + c;
            float4 b4 = make_float4(0.f,0.f,0.f,0.f);
            if (gk < K) {
                const float* brow = Bm + (long long)gk * ldb;
                if (bvec && (gc + 3 < N)) b4 = *(const float4*)(brow + gc);
                else {
                    float t0[4] = {0.f,0.f,0.f,0.f};
#pragma unroll
                    for (int i=0;i<4;i++) if (gc+i < N) t0[i] = brow[gc+i];
                    b4 = make_float4(t0[0],t0[1],t0[2],t0[3]);
                }
            }
            Bs[r][c+0]=b4.x; Bs[r][c+1]=b4.y; Bs[r][c+2]=b4.z; Bs[r][c+3]=b4.w;
        }
        __syncthreads();
#pragma unroll
        for (int kk=0;kk<BK;kk++) {
            float a[TM], b[TN];
#pragma unroll
            for (int p=0;p<TM/4;p++) {
                float4 t4 = *(const float4*)&As[kk][ty*TM + 4*p];
                a[4*p]=t4.x; a[4*p+1]=t4.y; a[4*p+2]=t4.z; a[4*p+3]=t4.w;
            }
#pragma unroll
            for (int p=0;p<TN/4;p++) {
                float4 t4 = *(const float4*)&Bs[kk][tx*TN + 4*p];
                b[4*p]=t4.x; b[4*p+1]=t4.y; b[4*p+2]=t4.z; b[4*p+3]=t4.w;
            }
#pragma unroll
            for (int i=0;i<TM;i++)
#pragma unroll
                for (int j=0;j<TN;j++) acc[i][j] = fmaf(a[i], b[j], acc[i][j]);
        }
        __syncthreads();
    }
#pragma unroll
    for (int i=0;i<TM;i++) {
        const int r = m0 + ty*TM + i;
        if (r >= M) continue;
#pragma unroll
        for (int j=0;j<TN;j++) {
            const int c = n0 + tx*TN + j;
            if (c >= N) continue;
            float val = acc[i][j];
            if (bias) val += bias[c];
            if (EPI == 3) val += src[(long long)r*ldsrc + c];
            if constexpr (EPI == 3) {
                u16 h, l; split2(val, h, l);
                const long long os = (long long)r*2*ldc + ((c>>5)<<6) + (c&31);
                Csp[os] = h; Csp[os+32] = l;
            } else {
                C[(long long)r*ldc + c] = val;
            }
        }
    }
}

// ---------------------------------------------------------------- weights: W[Kin][Nin] -> T{hi,lo}[Nout][Kld] bf16 (zero-padded)
__global__ __launch_bounds__(256)
void split_transpose_w(const float* __restrict__ W, u16* __restrict__ Thi,
                       u16* __restrict__ Tlo, int Kin, int Nin, int Kld)
{
    __shared__ float tile[64][33];
    const int k0 = blockIdx.x*64, n0 = blockIdx.y*32;
    const int t = threadIdx.x;
    const int ln = t & 31, lk = t >> 5;
#pragma unroll
    for (int i=0;i<8;i++) {
        const int k = k0 + lk + i*8, n = n0 + ln;
        tile[lk + i*8][ln] = (k < Kin && n < Nin) ? W[(long long)k*Nin + n] : 0.f;
    }
    __syncthreads();
    const int wn = t >> 3, wk = (t & 7) * 8;
    u16x8 hv, lv;
#pragma unroll
    for (int i=0;i<8;i++){
        u16 h, l; split2(tile[wk + i][wn], h, l);
        hv[i] = h; lv[i] = l;
    }
    *(u16x8*)&Thi[(long long)(n0+wn)*Kld + k0 + wk] = hv;
    *(u16x8*)&Tlo[(long long)(n0+wn)*Kld + k0 + wk] = lv;
}

// ---------------------------------------------------------------- split rows -> interleaved [hi32|lo32] per 32-granule
__global__ __launch_bounds__(256)
void split_rows_il(const float* __restrict__ x, u16* __restrict__ sp, long long ngran)
{
    for (long long g = blockIdx.x*256 + threadIdx.x; g < ngran; g += (long long)gridDim.x*256) {
        const float4* s4 = (const float4*)(x + g*32);
        u16* o = sp + g*64;
        u16x8 hv[4], lv[4];
#pragma unroll
        for (int q=0;q<4;q++){
            const float4 f0 = s4[2*q], f1 = s4[2*q+1];
            const float fa[8]={f0.x,f0.y,f0.z,f0.w,f1.x,f1.y,f1.z,f1.w};
#pragma unroll
            for (int e=0;e<8;e++){ u16 hh,ll2; split2(fa[e],hh,ll2); hv[q][e]=hh; lv[q][e]=ll2; }
        }
#pragma unroll
        for (int q=0;q<4;q++){ *(u16x8*)(o+q*8)=hv[q]; *(u16x8*)(o+32+q*8)=lv[q]; }
    }
}

// ---------------------------------------------------------------- big bf16x3 MFMA GEMM: BM=BN=128, XCD swizzle, reg prefetch
// A interleaved [M][2K]; B pre-split BT{hi,lo}[N][K]. C fp32. ACT: 1 relu, 2 tanh.
// grid = 1-D, (M/128)*8 blocks; N must give exactly 8 col-blocks; rpx = (M/128)/8.
template<int ACT>
__global__ __launch_bounds__(256, 3)
void gemm3s128(const u16* __restrict__ Asp, int lda2,
               const u16* __restrict__ BThi, const u16* __restrict__ BTlo,
               float* __restrict__ C, int ldc, int N, int K, int rpx)
{
    constexpr int PK=40;
    __shared__ __align__(16) u16 Ah[128*PK];
    __shared__ __align__(16) u16 Al[128*PK];
    __shared__ __align__(16) u16 Bh[128*PK];
    __shared__ __align__(16) u16 Bl[128*PK];

    // XCD-bijective swizzle: xcd = wgid&7 owns rpx contiguous row-panels;
    // its 8 col-blocks per panel are consecutive j -> same-XCD L2 holds the panel.
    const int wgid = blockIdx.x;
    const int xcd  = wgid & 7;
    const int j    = wgid >> 3;
    const int m0   = (xcd*rpx + (j>>3)) * 128;
    const int n0   = (j & 7) * 128;

    const int tid = threadIdx.x;
    const int wave = tid>>6, lane = tid&63;
    const int wm = wave>>1, wn = wave&1;
    const int r16 = lane&15, g = lane>>4;

    f32x4 acc[4][4];
#pragma unroll
    for (int i=0;i<4;i++)
#pragma unroll
      for (int jj=0;jj<4;jj++) acc[i][jj] = f32x4{0.f,0.f,0.f,0.f};

    const int r = tid>>1, half = tid&1;
    const u16* pA = Asp + (long long)(m0+r)*lda2 + half*32;
    const u16* pB = (half ? BTlo : BThi) + (long long)(n0+r)*K;
    u16* sA = (half ? Al : Ah) + r*PK;
    u16* sB = (half ? Bl : Bh) + r*PK;

    u16x8 ra0,ra1,ra2,ra3, rb0,rb1,rb2,rb3;
    {
        ra0=*(const u16x8*)pA;      ra1=*(const u16x8*)(pA+8);
        ra2=*(const u16x8*)(pA+16); ra3=*(const u16x8*)(pA+24);
        rb0=*(const u16x8*)pB;      rb1=*(const u16x8*)(pB+8);
        rb2=*(const u16x8*)(pB+16); rb3=*(const u16x8*)(pB+24);
    }
    for (int k0=0; k0<K; k0+=32) {
        __syncthreads();                               // previous compute done
        *(u16x8*)(sA)=ra0; *(u16x8*)(sA+8)=ra1; *(u16x8*)(sA+16)=ra2; *(u16x8*)(sA+24)=ra3;
        *(u16x8*)(sB)=rb0; *(u16x8*)(sB+8)=rb1; *(u16x8*)(sB+16)=rb2; *(u16x8*)(sB+24)=rb3;
        if (k0+32 < K) {                               // prefetch next tile (hides under MFMA)
            const u16* a = pA + (long long)(k0+32)*2;
            const u16* b = pB + (k0+32);
            ra0=*(const u16x8*)a;      ra1=*(const u16x8*)(a+8);
            ra2=*(const u16x8*)(a+16); ra3=*(const u16x8*)(a+24);
            rb0=*(const u16x8*)b;      rb1=*(const u16x8*)(b+8);
            rb2=*(const u16x8*)(b+16); rb3=*(const u16x8*)(b+24);
        }
        __syncthreads();                               // LDS ready
        s16x8 bhf[4], blf[4];
#pragma unroll
        for (int nf=0;nf<4;nf++){
            bhf[nf] = *(const s16x8*)&Bh[(wn*64 + nf*16 + r16)*PK + g*8];
            blf[nf] = *(const s16x8*)&Bl[(wn*64 + nf*16 + r16)*PK + g*8];
        }
#pragma unroll
        for (int mf=0;mf<4;mf++){
            const s16x8 ah = *(const s16x8*)&Ah[(wm*64 + mf*16 + r16)*PK + g*8];
            const s16x8 al = *(const s16x8*)&Al[(wm*64 + mf*16 + r16)*PK + g*8];
#pragma unroll
            for (int nf=0;nf<4;nf++){
                acc[mf][nf] = __builtin_amdgcn_mfma_f32_16x16x32_bf16(ah, bhf[nf], acc[mf][nf],0,0,0);
                acc[mf][nf] = __builtin_amdgcn_mfma_f32_16x16x32_bf16(ah, blf[nf], acc[mf][nf],0,0,0);
                acc[mf][nf] = __builtin_amdgcn_mfma_f32_16x16x32_bf16(al, bhf[nf], acc[mf][nf],0,0,0);
            }
        }
    }
    // epilogue: C/D layout col=lane&15, row=(lane>>4)*4+reg
#pragma unroll
    for (int mf=0;mf<4;mf++){
        const int rr = m0 + wm*64 + mf*16 + g*4;
#pragma unroll
        for (int nf=0;nf<4;nf++){
            const int cc = n0 + wn*64 + nf*16 + r16;
            if (cc >= N) continue;
#pragma unroll
            for (int i=0;i<4;i++){
                float val = acc[mf][nf][i];
                if (ACT==1) val = fmaxf(val,0.f);
                else if (ACT==2) val = tanh_fast(val);
                C[(long long)(rr+i)*ldc + cc] = val;
            }
        }
    }
}

// ---------------------------------------------------------------- small-M bf16x3 GEMM: BM=64, BN=128. A interleaved.
// ACT: 0 none,1 relu,2 tanh,3 per-1024-seg (relu,tanh,tanh,relu)
// EPI: 0 fp32 out; 1 fp32 + interleaved split out; 2 mul-src then fp32 + split out.
template<int ACT, int EPI, bool BIAS>
__global__ __launch_bounds__(256, 3)
void gemm3s64(const u16* __restrict__ Asp, int lda2,
              const u16* __restrict__ BThi, const u16* __restrict__ BTlo,
              const float* __restrict__ bias,
              const float* __restrict__ src, int ldsrc,
              float* __restrict__ C, u16* __restrict__ Csp,
              int ldc, int N, int K)
{
    constexpr int PK=40;
    __shared__ __align__(16) u16 Ah[64*PK];
    __shared__ __align__(16) u16 Al[64*PK];
    __shared__ __align__(16) u16 Bh[128*PK];
    __shared__ __align__(16) u16 Bl[128*PK];

    const int tid = threadIdx.x;
    const int m0 = blockIdx.y*64, n0 = blockIdx.x*128;
    const int wave = tid>>6, lane = tid&63;
    const int wm = wave>>1, wn = wave&1;
    const int r16 = lane&15, g = lane>>4;

    f32x4 acc[2][4];
#pragma unroll
    for (int i=0;i<2;i++)
#pragma unroll
      for (int jj=0;jj<4;jj++) acc[i][jj] = f32x4{0.f,0.f,0.f,0.f};

    const int ar = tid>>2, aq = tid&3;
    const u16* pA = Asp + (long long)(m0+ar)*lda2 + aq*16;
    u16* sA = ((aq<2) ? Ah : Al) + ar*PK + (aq&1)*16;
    const int rb = tid>>1, hb = tid&1;
    const u16* pB = (hb ? BTlo : BThi) + (long long)(n0+rb)*K;
    u16* sB = (hb ? Bl : Bh) + rb*PK;

    for (int k0=0; k0<K; k0+=32) {
        __syncthreads();
        *(u16x8*)(sA)   = *(const u16x8*)(pA + (long long)k0*2);
        *(u16x8*)(sA+8) = *(const u16x8*)(pA + (long long)k0*2 + 8);
        *(u16x8*)(sB)    = *(const u16x8*)(pB + k0);
        *(u16x8*)(sB+8)  = *(const u16x8*)(pB + k0 + 8);
        *(u16x8*)(sB+16) = *(const u16x8*)(pB + k0 + 16);
        *(u16x8*)(sB+24) = *(const u16x8*)(pB + k0 + 24);
        __syncthreads();
        s16x8 bhf[4], blf[4];
#pragma unroll
        for (int nf=0;nf<4;nf++){
            bhf[nf] = *(const s16x8*)&Bh[(wn*64 + nf*16 + r16)*PK + g*8];
            blf[nf] = *(const s16x8*)&Bl[(wn*64 + nf*16 + r16)*PK + g*8];
        }
#pragma unroll
        for (int mf=0;mf<2;mf++){
            const s16x8 ah = *(const s16x8*)&Ah[(wm*32 + mf*16 + r16)*PK + g*8];
            const s16x8 al = *(const s16x8*)&Al[(wm*32 + mf*16 + r16)*PK + g*8];
#pragma unroll
            for (int nf=0;nf<4;nf++){
                acc[mf][nf] = __builtin_amdgcn_mfma_f32_16x16x32_bf16(ah, bhf[nf], acc[mf][nf],0,0,0);
                acc[mf][nf] = __builtin_amdgcn_mfma_f32_16x16x32_bf16(ah, blf[nf], acc[mf][nf],0,0,0);
                acc[mf][nf] = __builtin_amdgcn_mfma_f32_16x16x32_bf16(al, bhf[nf], acc[mf][nf],0,0,0);
            }
        }
    }
#pragma unroll
    for (int mf=0;mf<2;mf++){
        const int rr = m0 + wm*32 + mf*16 + g*4;
#pragma unroll
        for (int nf=0;nf<4;nf++){
            const int cc = n0 + wn*64 + nf*16 + r16;
            if (cc >= N) continue;
            const float bval = BIAS ? bias[cc] : 0.f;
#pragma unroll
            for (int i=0;i<4;i++){
                float val = acc[mf][nf][i] + bval;
                if (ACT == 1) val = fmaxf(val, 0.f);
                else if (ACT == 2) val = tanh_fast(val);
                else if (ACT == 3) {
                    const int seg = cc >> 10;
                    val = (seg==0 || seg==3) ? fmaxf(val, 0.f) : tanh_fast(val);
                }
                if (EPI == 2) val *= src[(long long)(rr+i)*ldsrc + cc];
                C[(long long)(rr+i)*ldc + cc] = val;
                if (EPI >= 1) {
                    u16 h, l; split2(val, h, l);
                    const long long os = (long long)(rr+i)*2*ldc + ((cc>>5)<<6) + (cc&31);
                    Csp[os] = h; Csp[os+32] = l;
                }
            }
        }
    }
}

// ---------------------------------------------------------------- fused GRU step (t>=1)
__global__ __launch_bounds__(192)
void gru_step(const float* __restrict__ hprev, const u16* __restrict__ hsp,
              const u16* __restrict__ whhThi, const u16* __restrict__ whhTlo,
              const float* __restrict__ gi, int t, const float* __restrict__ bhh,
              float* __restrict__ hout, u16* __restrict__ hosp)
{
    constexpr int PK = 40;
    __shared__ __align__(16) u16 smem[8*32*PK];
    u16* Ah = smem;
    u16* Al = smem + 32*PK;
    const int tid = threadIdx.x, seg = tid>>6, lane = tid&63;
    u16* Bh = smem + 2*32*PK + seg*2*32*PK;
    u16* Bl = Bh + 32*PK;
    const int j0 = blockIdx.x*32, b0 = blockIdx.y*32;
    const int r16 = lane&15, g = lane>>4;
    f32x4 acc[2][2];
#pragma unroll
    for (int i=0;i<2;i++)
#pragma unroll
      for (int j=0;j<2;j++) acc[i][j] = f32x4{0.f,0.f,0.f,0.f};

    const int rA = lane>>1, hA = lane&1;
    const u16* pA = hsp + (long long)(b0+rA)*(2*H_) + hA*32;
    u16* sA = (hA ? Al : Ah) + rA*PK;
    const int sr = lane>>1, sc = (lane&1)*16;
    const u16* pBh = whhThi + (long long)(seg*H_ + j0 + sr)*H_ + sc;
    const u16* pBl = whhTlo + (long long)(seg*H_ + j0 + sr)*H_ + sc;
    u16* sBh = Bh + sr*PK + sc;
    u16* sBl = Bl + sr*PK + sc;

    for (int k0=0; k0<H_; k0+=32) {
        __syncthreads();
        if (seg == 0) {
            const u16* a = pA + (long long)k0*2;
            *(u16x8*)(sA)    = *(const u16x8*)(a);
            *(u16x8*)(sA+8)  = *(const u16x8*)(a+8);
            *(u16x8*)(sA+16) = *(const u16x8*)(a+16);
            *(u16x8*)(sA+24) = *(const u16x8*)(a+24);
        }
        *(u16x8*)(sBh)   = *(const u16x8*)(pBh + k0);
        *(u16x8*)(sBh+8) = *(const u16x8*)(pBh + k0 + 8);
        *(u16x8*)(sBl)   = *(const u16x8*)(pBl + k0);
        *(u16x8*)(sBl+8) = *(const u16x8*)(pBl + k0 + 8);
        __syncthreads();
        s16x8 bh[2], bl[2];
#pragma unroll
        for (int nf=0;nf<2;nf++){
            bh[nf] = *(const s16x8*)&Bh[(nf*16 + r16)*PK + g*8];
            bl[nf] = *(const s16x8*)&Bl[(nf*16 + r16)*PK + g*8];
        }
#pragma unroll
        for (int mf=0;mf<2;mf++){
            const s16x8 ah = *(const s16x8*)&Ah[(mf*16 + r16)*PK + g*8];
            const s16x8 al = *(const s16x8*)&Al[(mf*16 + r16)*PK + g*8];
#pragma unroll
            for (int nf=0;nf<2;nf++){
                acc[mf][nf] = __builtin_amdgcn_mfma_f32_16x16x32_bf16(ah, bh[nf], acc[mf][nf], 0,0,0);
                acc[mf][nf] = __builtin_amdgcn_mfma_f32_16x16x32_bf16(ah, bl[nf], acc[mf][nf], 0,0,0);
                acc[mf][nf] = __builtin_amdgcn_mfma_f32_16x16x32_bf16(al, bh[nf], acc[mf][nf], 0,0,0);
            }
        }
    }
    __syncthreads();
    float* ghb = (float*)smem;          // 12 KB <= 20 KB
#pragma unroll
    for (int mf=0;mf<2;mf++)
#pragma unroll
      for (int nf=0;nf<2;nf++)
#pragma unroll
        for (int i=0;i<4;i++)
            ghb[(seg*32 + mf*16 + g*4 + i)*32 + nf*16 + r16] = acc[mf][nf][i];
    __syncthreads();
    for (int idx = tid; idx < 1024; idx += 192) {
        const int r = idx>>5, c = idx&31;
        const int b = b0 + r, j = j0 + c;
        const float* gib = gi + ((long long)b*L_ + t)*H3 + j;
        const float ir = gib[0], iz = gib[H_], inn = gib[2*H_];
        const float hr = ghb[(0*32+r)*32+c] + bhh[j];
        const float hz = ghb[(1*32+r)*32+c] + bhh[j+H_];
        const float hn = ghb[(2*32+r)*32+c] + bhh[j+2*H_];
        const float hp = hprev[(long long)b*H_ + j];
        const float rg = 1.f/(1.f+expf(-(ir+hr)));
        const float zg = 1.f/(1.f+expf(-(iz+hz)));
        const float nn = tanhf(inn + rg*hn);
        const float ho = (1.f - zg)*nn + zg*hp;
        hout[(long long)b*H_ + j] = ho;
        u16 hh, hl; split2(ho, hh, hl);
        const long long ob = (long long)b*(2*H_) + ((j>>5)<<6) + (j&31);
        hosp[ob] = hh; hosp[ob+32] = hl;
    }
}

// ---------------------------------------------------------------- GRU t=0 (h=0)
__global__ __launch_bounds__(256)
void gru_t0(const float* __restrict__ gi, const float* __restrict__ bhh,
            float* __restrict__ h, u16* __restrict__ hsp)
{
    const int idx = blockIdx.x*256 + threadIdx.x;
    const int b = idx >> 10, j = idx & (H_-1);
    const float* gib = gi + ((long long)b*L_)*H3 + j;
    const float ir = gib[0], iz = gib[H_], inn = gib[2*H_];
    const float rg = 1.f/(1.f+expf(-(ir+bhh[j])));
    const float zg = 1.f/(1.f+expf(-(iz+bhh[j+H_])));
    const float nn = tanhf(inn + rg*bhh[j+2*H_]);
    const float ho = (1.f - zg)*nn;
    h[idx] = ho;
    u16 hh, hl; split2(ho, hh, hl);
    const long long ob = (long long)b*(2*H_) + ((j>>5)<<6) + (j&31);
    hsp[ob] = hh; hsp[ob+32] = hl;
}

// ---------------------------------------------------------------- qbias = [bq_net, 0, 0, 0]
__global__ __launch_bounds__(256)
void build_qbias(const float* __restrict__ bq, float* __restrict__ qb)
{
    const int i = blockIdx.x*256 + threadIdx.x;
    if (i < 4096) qb[i] = (i < 1024) ? bq[i] : 0.f;
}

// ---------------------------------------------------------------- s_proj = tanh(b4 @ ws_b)
__global__ __launch_bounds__(256)
void sproj_kernel(const float* __restrict__ bIn, const float* __restrict__ wsB,
                  float* __restrict__ sProj)
{
    const int row = blockIdx.x;
    const float* br = bIn + (long long)row * 6;
    const float b0=br[0], b1=br[1], b2=br[2], b3=br[3];
    for (int h = threadIdx.x; h < H_; h += 256) {
        float val = b0*wsB[h] + b1*wsB[H_+h] + b2*wsB[2*H_+h] + b3*wsB[3*H_+h];
        sProj[(long long)row*H_ + h] = tanhf(val);
    }
}

// ---------------------------------------------------------------- fused Gram: s_rel + v_rel
__global__ __launch_bounds__(256)
void gram_rel_kernel(const float* __restrict__ sProj, const float* __restrict__ sQ,
                     const float* __restrict__ vProj, const float* __restrict__ vQ,
                     int ldq, float* __restrict__ rel)
{
    __shared__ float As[16][68];
    __shared__ float Bs[16][68];
    const int b = blockIdx.z;
    const int n0 = blockIdx.y * 64, m0 = blockIdx.x * 64;
    const int tid = threadIdx.x;
    const int lr = tid / 4, lk = (tid % 4) * 4;
    const int tx = tid % 16, ty = tid / 16;
    float acc[4][4];
#pragma unroll
    for (int i=0;i<4;i++)
#pragma unroll
      for (int j=0;j<4;j++) acc[i][j]=0.f;

    for (int pass=0; pass<2; ++pass) {
        const float* P  = pass ? vProj : sProj;
        const float* Q  = (pass ? vQ : sQ) + (long long)b * ldq;
        const float* Pb = P + (long long)b * N_ * H_;
        for (int k0=0; k0<H_; k0+=16) {
            const float4 qv = *(const float4*)(Q + k0 + lk);
            float4 a4 = make_float4(0,0,0,0), b4 = make_float4(0,0,0,0);
            if (n0 + lr < N_) a4 = *(const float4*)(Pb + (long long)(n0+lr)*H_ + k0 + lk);
            if (m0 + lr < N_) b4 = *(const float4*)(Pb + (long long)(m0+lr)*H_ + k0 + lk);
            As[lk+0][lr]=a4.x*qv.x; As[lk+1][lr]=a4.y*qv.y; As[lk+2][lr]=a4.z*qv.z; As[lk+3][lr]=a4.w*qv.w;
            Bs[lk+0][lr]=b4.x; Bs[lk+1][lr]=b4.y; Bs[lk+2][lr]=b4.z; Bs[lk+3][lr]=b4.w;
            __syncthreads();
#pragma unroll
            for (int kk=0;kk<16;kk++){
                const float4 av4 = *(const float4*)&As[kk][ty*4];
                const float4 bv4 = *(const float4*)&Bs[kk][tx*4];
                const float a[4]={av4.x,av4.y,av4.z,av4.w};
                const float bb[4]={bv4.x,bv4.y,bv4.z,bv4.w};
#pragma unroll
                for (int i=0;i<4;i++)
#pragma unroll
                  for (int j=0;j<4;j++) acc[i][j] = fmaf(a[i],bb[j],acc[i][j]);
            }
            __syncthreads();
        }
    }
#pragma unroll
    for (int i=0;i<4;i++){
        const int n = n0 + ty*4 + i; if (n>=N_) continue;
#pragma unroll
        for (int j=0;j<4;j++){
            const int m = m0 + tx*4 + j; if (m>=N_) continue;
            rel[((long long)b*N_ + n)*N_ + m] = acc[i][j];
        }
    }
}

// ---------------------------------------------------------------- softmax over m
__global__ __launch_bounds__(256)
void softmax_m_kernel(float* __restrict__ rel)
{
    const int w = threadIdx.x >> 6, l = threadIdx.x & 63;
    float* r = rel + ((long long)blockIdx.x*4 + w)*N_;
    const float v0 = r[l];
    const float v1 = (l + 64 < N_) ? r[l+64] : -INFINITY;
    float mx = fmaxf(v0, v1);
    for (int s=32;s;s>>=1) mx = fmaxf(mx, __shfl_xor(mx, s));
    const float e0 = expf(v0-mx);
    const float e1 = (l+64<N_) ? expf(v1-mx) : 0.f;
    float sum = e0+e1;
    for (int s=32;s;s>>=1) sum += __shfl_xor(sum, s);
    const float inv = 1.f/sum;
    r[l] = e0*inv;
    if (l+64 < N_) r[l+64] = e1*inv;
}

// ---------------------------------------------------------------- att logits
__global__ __launch_bounds__(256)
void att_logits_kernel(const float* __restrict__ av, const float* __restrict__ aq,
                       int ldq, const float* __restrict__ waOut, float* __restrict__ out)
{
    const int w = threadIdx.x >> 6, l = threadIdx.x & 63;
    const int row = blockIdx.x*4 + w;
    const int b = row / N_;
    const float* avr = av + (long long)row*H_;
    const float* aqr = aq + (long long)b*ldq;
    float acc = 0.f;
#pragma unroll
    for (int i=0;i<4;i++){
        const int h = i*256 + l*4;
        const float4 a4 = *(const float4*)(avr+h);
        const float4 q4 = *(const float4*)(aqr+h);
        const float4 w4 = *(const float4*)(waOut+h);
        acc += a4.x*q4.x*w4.x + a4.y*q4.y*w4.y + a4.z*q4.z*w4.z + a4.w*q4.w*w4.w;
    }
    for (int s=32;s;s>>=1) acc += __shfl_xor(acc, s);
    if (l==0) out[row] = acc;
}

// ---------------------------------------------------------------- softmax over n
__global__ __launch_bounds__(128)
void softmax_n_kernel(const float* __restrict__ lg, float* __restrict__ att)
{
    __shared__ float s[128];
    const int b = blockIdx.x, t = threadIdx.x;
    const float v = (t < N_) ? lg[(long long)b*N_+t] : -INFINITY;
    s[t]=v; __syncthreads();
    for (int st=64;st;st>>=1){ if (t<st) s[t]=fmaxf(s[t],s[t+st]); __syncthreads(); }
    const float mx = s[0]; __syncthreads();
    const float e = (t<N_)? expf(v-mx) : 0.f;
    s[t]=e; __syncthreads();
    for (int st=64;st;st>>=1){ if (t<st) s[t]+=s[t+st]; __syncthreads(); }
    const float inv = 1.f/s[0];
    if (t<N_) att[(long long)b*N_+t] = e*inv;
}

// ---------------------------------------------------------------- v_emb from interleaved v2sp, emit interleaved
__global__ __launch_bounds__(256)
void vemb_kernel(const float* __restrict__ att, const u16* __restrict__ v2sp,
                 u16* __restrict__ vesp)
{
    __shared__ float sa[N_];
    const int b = blockIdx.y, dt = blockIdx.x, tid = threadIdx.x;
    if (tid < N_) sa[tid] = att[(long long)b*N_+tid];
    __syncthreads();
    const int d = dt*256 + tid;
    const long long colo = (long long)((d>>5)<<6) + (d&31);
    const u16* vb = v2sp + (long long)b*N_*(2*OBJD) + colo;
    float acc = 0.f;
#pragma unroll 4
    for (int n=0;n<N_;n++) {
        const u16* p = vb + (long long)n*(2*OBJD);
        acc += sa[n]*(b2f(p[0]) + b2f(p[32]));
    }
    u16 h, l; split2(acc, h, l);
    const long long o = (long long)b*(2*OBJD) + colo;
    vesp[o] = h; vesp[o+32] = l;
}

// ================================================================ launcher
extern "C" void kernel_launch(void* const* d_in, const int* in_sizes, int n_in,
                              void* d_out, int out_size, void* d_ws, size_t ws_size,
                              hipStream_t stream)
{
    const float* v      = (const float*)d_in[0];
    const float* bbox   = (const float*)d_in[1];
    const int*   q      = (const int*)  d_in[3];
    const float* emb    = (const float*)d_in[5];
    const float* wih    = (const float*)d_in[6];
    const float* whh    = (const float*)d_in[7];
    const float* bih    = (const float*)d_in[8];
    const float* bhh    = (const float*)d_in[9];
    const float* wq_net = (const float*)d_in[10];
    const float* bq_net = (const float*)d_in[11];
    const float* ws_b   = (const float*)d_in[12];
    const float* ws_q   = (const float*)d_in[13];
    const float* wv_v   = (const float*)d_in[14];
    const float* wv_q   = (const float*)d_in[15];
    const float* wa_v   = (const float*)d_in[16];
    const float* wa_q   = (const float*)d_in[17];
    const float* wa_out = (const float*)d_in[18];
    const float* wv_net = (const float*)d_in[19];
    const float* bv_net = (const float*)d_in[20];
    const float* wc1    = (const float*)d_in[21];
    const float* bc1    = (const float*)d_in[22];
    const float* wc2    = (const float*)d_in[23];
    const float* bc2    = (const float*)d_in[24];
    float* out = (float*)d_out;
    (void)in_sizes; (void)n_in; (void)out_size; (void)ws_size; (void)bih;

    float* ws = (float*)d_ws;
    size_t off = 0;
    auto alloc = [&](size_t n){ float* p = ws + off; off += (n + 63) & ~(size_t)63; return p; };
    float* gi    = alloc((size_t)B_*L_*H3);
    float* h_a   = alloc((size_t)B_*H_);
    float* h_b   = alloc((size_t)B_*H_);
    u16* hsp_a = (u16*)alloc((size_t)B_*H_);         // B x 2H u16
    u16* hsp_b = (u16*)alloc((size_t)B_*H_);
    float* qcat  = alloc((size_t)B_*4096);
    float* qbias = alloc(4096);
    float* sproj = alloc((size_t)B_*N_*H_);
    float* vproj = alloc((size_t)B_*N_*H_);
    float* relb  = alloc((size_t)B_*N_*N_);
    u16* vsp  = (u16*)alloc((size_t)B_*N_*OBJD);     // interleaved; reused as v2sp
    float* avb   = sproj;                            // reuse
    float* attl  = alloc((size_t)B_*N_);
    float* vatt  = alloc((size_t)B_*N_);
    u16* vembsp = (u16*)alloc((size_t)B_*OBJD);
    float* jointf = alloc((size_t)B_*H_);
    u16* jointsp = (u16*)alloc((size_t)B_*H_);
    float* c1f   = alloc((size_t)B_*2*H_);
    u16* c1sp = (u16*)alloc((size_t)B_*2*H_);
    // weight splits (bf16, transposed, two-array)
    u16* whhThi = (u16*)alloc((size_t)H3*H_/2);
    u16* whhTlo = (u16*)alloc((size_t)H3*H_/2);
    u16* qcThi  = (u16*)alloc((size_t)4096*H_/2);
    u16* qcTlo  = (u16*)alloc((size_t)4096*H_/2);
    u16* wvvThi = (u16*)alloc((size_t)H_*OBJD/2);
    u16* wvvTlo = (u16*)alloc((size_t)H_*OBJD/2);
    u16* wavThi = (u16*)alloc((size_t)H_*OBJD/2);
    u16* wavTlo = (u16*)alloc((size_t)H_*OBJD/2);
    u16* wvnThi = (u16*)alloc((size_t)H_*OBJD/2);
    u16* wvnTlo = (u16*)alloc((size_t)H_*OBJD/2);
    u16* wc1Thi = (u16*)alloc((size_t)2*H_*H_/2);
    u16* wc1Tlo = (u16*)alloc((size_t)2*H_*H_/2);
    u16* wc2Thi = (u16*)alloc((size_t)3200*2*H_/2);
    u16* wc2Tlo = (u16*)alloc((size_t)3200*2*H_/2);

    // ---- weight prep
    split_transpose_w<<<dim3(H_/64, H3/32),256,0,stream>>>(whh, whhThi, whhTlo, H_, H3, H_);
    split_transpose_w<<<dim3(H_/64, H_/32),256,0,stream>>>(wq_net, qcThi + (size_t)0*H_*H_, qcTlo + (size_t)0*H_*H_, H_, H_, H_);
    split_transpose_w<<<dim3(H_/64, H_/32),256,0,stream>>>(ws_q,   qcThi + (size_t)1*H_*H_, qcTlo + (size_t)1*H_*H_, H_, H_, H_);
    split_transpose_w<<<dim3(H_/64, H_/32),256,0,stream>>>(wv_q,   qcThi + (size_t)2*H_*H_, qcTlo + (size_t)2*H_*H_, H_, H_, H_);
    split_transpose_w<<<dim3(H_/64, H_/32),256,0,stream>>>(wa_q,   qcThi + (size_t)3*H_*H_, qcTlo + (size_t)3*H_*H_, H_, H_, H_);
    split_transpose_w<<<dim3(OBJD/64, H_/32),256,0,stream>>>(wv_v, wvvThi, wvvTlo, OBJD, H_, OBJD);
    split_transpose_w<<<dim3(OBJD/64, H_/32),256,0,stream>>>(wa_v, wavThi, wavTlo, OBJD, H_, OBJD);
    split_transpose_w<<<dim3(OBJD/64, H_/32),256,0,stream>>>(wv_net, wvnThi, wvnTlo, OBJD, H_, OBJD);
    split_transpose_w<<<dim3(H_/64, 2*H_/32),256,0,stream>>>(wc1, wc1Thi, wc1Tlo, H_, 2*H_, H_);
    split_transpose_w<<<dim3(2*H_/64, 3200/32),256,0,stream>>>(wc2, wc2Thi, wc2Tlo, 2*H_, NANS_, 2*H_);
    split_rows_il<<<2048,256,0,stream>>>(v, vsp, (long long)B_*N_*OBJD/32);
    build_qbias<<<16,256,0,stream>>>(bq_net, qbias);

    // ---- gi = emb[q] @ wih + bih  (fp32, gather)
    {
        dim3 g(H3/128, (B_*L_+127)/128, 1);
        gemm_f32<128,128,16,8,8,0,true><<<g,256,0,stream>>>(
            emb,0,EMBD, wih,0,H3, bih, nullptr,0,0, gi,nullptr,0,H3, B_*L_, H3, EMBD, q);
    }
    // ---- GRU
    gru_t0<<<(B_*H_)/256,256,0,stream>>>(gi, bhh, h_a, hsp_a);
    float* hp = h_a; u16* hpS = hsp_a;
    float* hn = h_b; u16* hnS = hsp_b;
    for (int t=1;t<L_;t++){
        gru_step<<<dim3(H_/32, B_/32),192,0,stream>>>(hp, hpS, whhThi, whhTlo,
                                                      gi, t, bhh, hn, hnS);
        float* tf=hp; hp=hn; hn=tf;
        u16* th=hpS; hpS=hnS; hnS=th;
    }
    // ---- qcat = [relu(q@wq+bq) | tanh(q@ws_q) | tanh(q@wv_q) | relu(q@wa_q)]
    gemm3s64<3,0,true><<<dim3(4096/128, B_/64),256,0,stream>>>(
        hpS, 2*H_, qcThi, qcTlo, qbias, nullptr,0,
        qcat, nullptr, 4096, 4096, H_);
    const float* qrepr = qcat;
    const float* sq    = qcat + 1024;
    const float* vq    = qcat + 2048;
    const float* aq    = qcat + 3072;

    sproj_kernel<<<B_*N_,256,0,stream>>>(bbox, ws_b, sproj);
    // ---- v_proj = tanh(v @ wv_v)   [128x128, XCD swizzle, prefetch]
    gemm3s128<2><<<(B_*N_/128)*8,256,0,stream>>>(
        vsp, 2*OBJD, wvvThi, wvvTlo, vproj, H_, H_, OBJD, (B_*N_/128)/8);
    // ---- rel logits + softmax
    gram_rel_kernel<<<dim3(2,2,B_),256,0,stream>>>(sproj, sq, vproj, vq, 4096, relb);
    softmax_m_kernel<<<(B_*N_)/4,256,0,stream>>>(relb);
    // ---- v2 = rel @ v + v  -> interleaved split only (vsp reused as v2sp)
    {
        dim3 g(OBJD/64, (N_+63)/64, B_);
        gemm_f32<64,64,16,4,4,3,false><<<g,256,0,stream>>>(
            relb,(long long)N_*N_,N_, v,(long long)N_*OBJD,OBJD, nullptr,
            v,(long long)N_*OBJD,OBJD, nullptr, vsp,
            (long long)N_*OBJD, OBJD, N_, OBJD, N_, nullptr);
    }
    // ---- av = relu(v2 @ wa_v)
    gemm3s128<1><<<(B_*N_/128)*8,256,0,stream>>>(
        vsp, 2*OBJD, wavThi, wavTlo, avb, H_, H_, OBJD, (B_*N_/128)/8);
    att_logits_kernel<<<(B_*N_)/4,256,0,stream>>>(avb, aq, 4096, wa_out, attl);
    softmax_n_kernel<<<B_,128,0,stream>>>(attl, vatt);
    vemb_kernel<<<dim3(OBJD/256,B_),256,0,stream>>>(vatt, vsp, vembsp);
    // ---- joint = relu(vemb@wv_net + bv) * qrepr   (+ split)
    gemm3s64<1,2,true><<<dim3(H_/128, B_/64),256,0,stream>>>(
        vembsp, 2*OBJD, wvnThi, wvnTlo, bv_net, qrepr, 4096,
        jointf, jointsp, H_, H_, OBJD);
    // ---- c1 = relu(joint@wc1 + bc1)  (+ split)
    gemm3s64<1,1,true><<<dim3(2*H_/128, B_/64),256,0,stream>>>(
        jointsp, 2*H_, wc1Thi, wc1Tlo, bc1, nullptr,0,
        c1f, c1sp, 2*H_, 2*H_, H_);
    // ---- logits = c1 @ wc2 + bc2
    gemm3s64<0,0,true><<<dim3(3200/128, B_/64),256,0,stream>>>(
        c1sp, 2*2*H_, wc2Thi, wc2Tlo, bc2, nullptr,0,
        out, nullptr, NANS_, NANS_, 2*H_);
}